// Round 7
// baseline (1739.325 us; speedup 1.0000x reference)
//
#include <hip/hip_runtime.h>
#include <hip/hip_bf16.h>

#define NN 100000
#define NE 1600000
#define NBUK 1563          // ceil(NN/64) 64-node dst buckets
#define NBB  49            // histogram blocks (32768 edges each)
#define BATCH 32768
#define CNTSZ (NBUK*NBB)   // 76587
#define CHUNK 75           // 75*1024 >= CNTSZ

using bf16 = __hip_bfloat16;
typedef unsigned short us8_t __attribute__((ext_vector_type(8)));
static __device__ __forceinline__ float b2f(bf16 v){ return __bfloat162float(v); }
static __device__ __forceinline__ bf16 f2b(float v){ return __float2bfloat16(v); }
static __device__ __forceinline__ float us2f(unsigned short u){
  unsigned x = ((unsigned)u)<<16; float f; __builtin_memcpy(&f,&x,4); return f;
}
static __device__ __forceinline__ unsigned short f2us(float v){
  bf16 b = f2b(v); unsigned short u; __builtin_memcpy(&u,&b,2); return u;
}

// canonical f32 weight-pool offsets (floats)
#define W1F   0
#define B1F   128
#define W2F   192
#define B2F   4288
#define W3F   4352
#define B3F   8448
#define FW1F  8512
#define FB1F  16704
#define FW2F  16832
#define FB2F  20928
#define WTOT  20960

// ---- dtype sniff (f32 vs bf16 storage) ----
__global__ void k_sniff(const unsigned short* __restrict__ xr, int* flag){
  __shared__ int found;
  if(threadIdx.x==0) found = 0;
  __syncthreads();
  int loc = 0;
  for(int i=threadIdx.x*2; i<200000; i+=2048){
    unsigned e = (xr[i]>>7)&0xFF;
    if(e==0xFFu || e==0u) loc = 1;
  }
  if(loc) found = 1;
  __syncthreads();
  if(threadIdx.x==0) *flag = found;   // 1 = f32 storage, 0 = bf16 storage
}

__global__ void k_convert_w(const void* p0,const void* p1,const void* p2,const void* p3,
                            const void* p4,const void* p5,const void* p6,const void* p7,
                            const void* p8,const void* p9,
                            const int* __restrict__ flag, float* __restrict__ Wc){
  const void* ps[10] = {p0,p1,p2,p3,p4,p5,p6,p7,p8,p9};
  const int off[11] = {W1F,B1F,W2F,B2F,W3F,B3F,FW1F,FB1F,FW2F,FB2F,WTOT};
  int f = *flag;
  for(int t=threadIdx.x; t<WTOT; t+=256){
    int seg = 0;
    while(off[seg+1] <= t) seg++;
    int j = t - off[seg];
    Wc[t] = f ? ((const float*)ps[seg])[j] : b2f(((const bf16*)ps[seg])[j]);
  }
}

// ---------------- bucket-CSR build ----------------
// per-(bucket, block) histogram
__global__ void k_bhist(const int* __restrict__ dst, int* __restrict__ cnt){
  __shared__ int hist[NBUK];
  for(int j=threadIdx.x; j<NBUK; j+=256) hist[j] = 0;
  __syncthreads();
  int e0 = blockIdx.x*BATCH;
  int e1 = min(NE, e0+BATCH);
  for(int e=e0+threadIdx.x; e<e1; e+=256) atomicAdd(&hist[dst[e]>>6], 1);
  __syncthreads();
  for(int j=threadIdx.x; j<NBUK; j+=256) cnt[j*NBB + blockIdx.x] = hist[j];
}
// exclusive scan over cnt (bucket-major) + bucketStart
__global__ void k_bscan(int* __restrict__ cnt, int* __restrict__ bucketStart){
  __shared__ int part[1024];
  int t = threadIdx.x;
  int lo = t*CHUNK, hi = min(CNTSZ, lo+CHUNK);
  int sum = 0;
  for(int j=lo; j<hi; j++) sum += cnt[j];
  part[t] = sum; __syncthreads();
  for(int off=1; off<1024; off<<=1){
    int v = (t>=off) ? part[t-off] : 0;
    __syncthreads();
    part[t] += v;
    __syncthreads();
  }
  int run = (t>0) ? part[t-1] : 0;   // exclusive base for this chunk
  for(int j=lo; j<hi; j++){
    int c = cnt[j];
    cnt[j] = run;
    if(j % NBB == 0) bucketStart[j/NBB] = run;
    run += c;
  }
  if(t==0) bucketStart[NBUK] = NE;
}
// place packed edges into bucket-grouped array; runs per (bucket,block) are exclusive
__global__ void k_bplace(const int* __restrict__ src, const int* __restrict__ dst,
                         const int* __restrict__ cnt, int* __restrict__ epk){
  __shared__ int cur[NBUK];
  for(int j=threadIdx.x; j<NBUK; j+=256) cur[j] = cnt[j*NBB + blockIdx.x];
  __syncthreads();
  int e0 = blockIdx.x*BATCH, e1 = min(NE, e0+BATCH);
  for(int e=e0+threadIdx.x; e<e1; e+=256){
    int d = dst[e];
    int pos = atomicAdd(&cur[d>>6], 1);
    epk[pos] = (src[e]<<6) | (d&63);
  }
}
// per-node degree (and dinv) from bucket-grouped edges — no global atomics
__global__ void k_degb(const int* __restrict__ bucketStart, const int* __restrict__ epk,
                       float* __restrict__ dinv){
  __shared__ int hist[64];
  if(threadIdx.x < 64) hist[threadIdx.x] = 0;
  __syncthreads();
  int b = blockIdx.x, beg = bucketStart[b], end = bucketStart[b+1];
  for(int p=beg+threadIdx.x; p<end; p+=256) atomicAdd(&hist[epk[p]&63], 1);
  __syncthreads();
  if(threadIdx.x < 64){
    int g = b*64 + threadIdx.x;
    if(g < NN) dinv[g] = rsqrtf((float)(hist[threadIdx.x] + 1));  // +1 self-loop
  }
}

// ---------------- layer 1 (propagate-then-transform; X has 2 channels) ----------------
__global__ void k_xd(const void* __restrict__ xv, const int* __restrict__ flag,
                     const float* __restrict__ dinv, float2* __restrict__ xd){
  int i = blockIdx.x*256 + threadIdx.x;
  if(i >= NN) return;
  float x0, x1;
  if(*flag){ float2 p = ((const float2*)xv)[i]; x0=p.x; x1=p.y; }
  else     { const bf16* xp=(const bf16*)xv; x0=b2f(xp[2*i]); x1=b2f(xp[2*i+1]); }
  float d = dinv[i];
  xd[i] = make_float2(x0*d, x1*d);
}
__global__ void k_prop_xb(const int* __restrict__ bucketStart, const int* __restrict__ epk,
                          const float2* __restrict__ xd, float2* __restrict__ y){
  __shared__ float ax[64], ay[64];
  if(threadIdx.x < 64){ ax[threadIdx.x]=0.0f; ay[threadIdx.x]=0.0f; }
  __syncthreads();
  int b = blockIdx.x, beg = bucketStart[b], end = bucketStart[b+1];
  for(int p=beg+threadIdx.x; p<end; p+=256){
    int pk = epk[p];
    float2 v = xd[pk>>6];
    int dl = pk&63;
    atomicAdd(&ax[dl], v.x);
    atomicAdd(&ay[dl], v.y);
  }
  __syncthreads();
  if(threadIdx.x < 64){
    int g = b*64 + threadIdx.x;
    if(g < NN){
      float2 s0 = xd[g];
      y[g] = make_float2(ax[threadIdx.x]+s0.x, ay[threadIdx.x]+s0.y);
    }
  }
}
__global__ void k_transform1b(const float2* __restrict__ y, const float* __restrict__ Wc,
                              const float* __restrict__ dinv, bf16* __restrict__ h){
  __shared__ float W1s[128];
  __shared__ float bs[64];
  if(threadIdx.x < 128) W1s[threadIdx.x] = Wc[W1F + threadIdx.x];
  if(threadIdx.x < 64)  bs[threadIdx.x]  = Wc[B1F + threadIdx.x];
  __syncthreads();
  int t = blockIdx.x*256 + threadIdx.x;   // grid NN*8 threads
  int i = t>>3, g = t&7;
  float2 yv = y[i];
  float d = dinv[i];
  us8_t o;
  #pragma unroll
  for(int j=0;j<8;j++){
    int c = g*8+j;
    o[j] = f2us(fmaxf(d*(yv.x*W1s[c] + yv.y*W1s[64+c]) + bs[c], 0.0f));
  }
  *(us8_t*)((unsigned short*)h + (size_t)i*64 + g*8) = o;
}

// ---------------- 64->64 transform (LDS-tiled GEMM, 4x4 tile/thread) ----------------
__global__ void __launch_bounds__(256) k_transform64(
    const bf16* __restrict__ h, const float* __restrict__ W,
    const float* __restrict__ dinv, bf16* __restrict__ s){
  __shared__ float Ws[64*64];
  __shared__ float hs[64][68];
  __shared__ float dl[64];
  int tid = threadIdx.x;
  for(int j=tid; j<4096; j+=256) Ws[j] = W[j];
  int row0 = blockIdx.x*64;
  if(tid < 64){ int r = row0+tid; dl[tid] = (r<NN)? dinv[r] : 0.0f; }
  for(int ch = tid; ch < 512; ch += 256){
    int r = ch>>3, c8 = (ch&7)*8;
    int gr = row0 + r;
    float f[8];
    if(gr < NN){
      us8_t v = *(const us8_t*)((const unsigned short*)h + (size_t)gr*64 + c8);
      #pragma unroll
      for(int j=0;j<8;j++) f[j] = us2f(v[j]);
    } else {
      #pragma unroll
      for(int j=0;j<8;j++) f[j] = 0.0f;
    }
    *(float4*)&hs[r][c8]   = make_float4(f[0],f[1],f[2],f[3]);
    *(float4*)&hs[r][c8+4] = make_float4(f[4],f[5],f[6],f[7]);
  }
  __syncthreads();
  int ty = tid>>4, tx = tid&15;
  float acc[4][4] = {{0}};
  #pragma unroll 8
  for(int k=0;k<64;k++){
    float4 b4 = *(const float4*)&Ws[k*64 + tx*4];
    float a0 = hs[ty*4+0][k];
    float a1 = hs[ty*4+1][k];
    float a2 = hs[ty*4+2][k];
    float a3 = hs[ty*4+3][k];
    acc[0][0] = fmaf(a0,b4.x,acc[0][0]); acc[0][1] = fmaf(a0,b4.y,acc[0][1]);
    acc[0][2] = fmaf(a0,b4.z,acc[0][2]); acc[0][3] = fmaf(a0,b4.w,acc[0][3]);
    acc[1][0] = fmaf(a1,b4.x,acc[1][0]); acc[1][1] = fmaf(a1,b4.y,acc[1][1]);
    acc[1][2] = fmaf(a1,b4.z,acc[1][2]); acc[1][3] = fmaf(a1,b4.w,acc[1][3]);
    acc[2][0] = fmaf(a2,b4.x,acc[2][0]); acc[2][1] = fmaf(a2,b4.y,acc[2][1]);
    acc[2][2] = fmaf(a2,b4.z,acc[2][2]); acc[2][3] = fmaf(a2,b4.w,acc[2][3]);
    acc[3][0] = fmaf(a3,b4.x,acc[3][0]); acc[3][1] = fmaf(a3,b4.y,acc[3][1]);
    acc[3][2] = fmaf(a3,b4.z,acc[3][2]); acc[3][3] = fmaf(a3,b4.w,acc[3][3]);
  }
  #pragma unroll
  for(int rr=0; rr<4; rr++){
    int r = row0 + ty*4 + rr;
    if(r < NN){
      float dv = dl[ty*4+rr];
      unsigned lo = f2us(acc[rr][0]*dv) | ((unsigned)f2us(acc[rr][1]*dv) << 16);
      unsigned hi = f2us(acc[rr][2]*dv) | ((unsigned)f2us(acc[rr][3]*dv) << 16);
      uint2 o; o.x = lo; o.y = hi;
      *(uint2*)((unsigned short*)s + (size_t)r*64 + tx*4) = o;
    }
  }
}

// ---------------- bucket aggregate + finalize (LDS accumulator) ----------------
// h[i] = relu(dinv[i]*(sum_{in} s[src] + s[i]) + b)
__global__ void __launch_bounds__(256) k_agg(const int* __restrict__ bucketStart,
                                             const int* __restrict__ epk,
                                             const bf16* __restrict__ s,
                                             const float* __restrict__ dinv,
                                             const float* __restrict__ bias,
                                             bf16* __restrict__ h){
  __shared__ float acc[64*64];   // 16 KB
  int tid = threadIdx.x;
  #pragma unroll
  for(int j=tid; j<4096; j+=256) acc[j] = 0.0f;
  __syncthreads();
  int b = blockIdx.x, beg = bucketStart[b], end = bucketStart[b+1];
  int lane = tid&63, wave = tid>>6;
  int total = end - beg, full = total & ~31;
  for(int off = wave*8; off < full; off += 32){
    int p = beg + off;
    int p0=epk[p],   p1=epk[p+1], p2=epk[p+2], p3=epk[p+3];
    int p4=epk[p+4], p5=epk[p+5], p6=epk[p+6], p7=epk[p+7];
    float v0 = b2f(s[(size_t)(p0>>6)*64 + lane]);
    float v1 = b2f(s[(size_t)(p1>>6)*64 + lane]);
    float v2 = b2f(s[(size_t)(p2>>6)*64 + lane]);
    float v3 = b2f(s[(size_t)(p3>>6)*64 + lane]);
    float v4 = b2f(s[(size_t)(p4>>6)*64 + lane]);
    float v5 = b2f(s[(size_t)(p5>>6)*64 + lane]);
    float v6 = b2f(s[(size_t)(p6>>6)*64 + lane]);
    float v7 = b2f(s[(size_t)(p7>>6)*64 + lane]);
    atomicAdd(&acc[(p0&63)*64 + lane], v0);
    atomicAdd(&acc[(p1&63)*64 + lane], v1);
    atomicAdd(&acc[(p2&63)*64 + lane], v2);
    atomicAdd(&acc[(p3&63)*64 + lane], v3);
    atomicAdd(&acc[(p4&63)*64 + lane], v4);
    atomicAdd(&acc[(p5&63)*64 + lane], v5);
    atomicAdd(&acc[(p6&63)*64 + lane], v6);
    atomicAdd(&acc[(p7&63)*64 + lane], v7);
  }
  if(wave == 0){
    for(int p = beg + full; p < end; p++){
      int pk = epk[p];
      atomicAdd(&acc[(pk&63)*64 + lane], b2f(s[(size_t)(pk>>6)*64 + lane]));
    }
  }
  __syncthreads();
  float bl = bias[lane];
  for(int r = wave; r < 64; r += 4){
    int g = b*64 + r;
    if(g < NN){
      float v = acc[r*64 + lane] + b2f(s[(size_t)g*64 + lane]);   // + self-loop
      v = fmaxf(dinv[g]*v + bl, 0.0f);
      int my = (int)f2us(v);
      unsigned short gg[8];
      #pragma unroll
      for(int j=0;j<8;j++) gg[j] = (unsigned short)__shfl(my, lane*8 + j, 64);
      if(lane < 8){
        us8_t o;
        #pragma unroll
        for(int j=0;j<8;j++) o[j] = gg[j];
        *(us8_t*)((unsigned short*)h + (size_t)g*64 + lane*8) = o;
      }
    }
  }
}

// ---------------- fc1: [NN x 64] @ [64 x 128] + b, relu -> f (bf16) ----------------
__global__ void __launch_bounds__(256) k_fc1(const bf16* __restrict__ h,
                                             const float* __restrict__ Wc,
                                             bf16* __restrict__ f){
  __shared__ float W1s[64*128];
  __shared__ float hs[64][68];
  __shared__ float bs[128];
  int tid = threadIdx.x;
  for(int j=tid; j<8192; j+=256) W1s[j] = Wc[FW1F+j];
  if(tid < 128) bs[tid] = Wc[FB1F+tid];
  int row0 = blockIdx.x*64;
  for(int ch = tid; ch < 512; ch += 256){
    int r = ch>>3, c8 = (ch&7)*8, gr = row0 + r;
    float fv[8];
    if(gr < NN){
      us8_t v = *(const us8_t*)((const unsigned short*)h + (size_t)gr*64 + c8);
      #pragma unroll
      for(int j=0;j<8;j++) fv[j] = us2f(v[j]);
    } else {
      #pragma unroll
      for(int j=0;j<8;j++) fv[j] = 0.0f;
    }
    *(float4*)&hs[r][c8]   = make_float4(fv[0],fv[1],fv[2],fv[3]);
    *(float4*)&hs[r][c8+4] = make_float4(fv[4],fv[5],fv[6],fv[7]);
  }
  __syncthreads();
  int ty = tid>>4, tx = tid&15;
  float acc[4][8] = {{0}};
  #pragma unroll 4
  for(int k=0;k<64;k++){
    float4 b0 = *(const float4*)&W1s[k*128 + tx*8];
    float4 b1 = *(const float4*)&W1s[k*128 + tx*8 + 4];
    float a0 = hs[ty*4+0][k], a1 = hs[ty*4+1][k];
    float a2 = hs[ty*4+2][k], a3 = hs[ty*4+3][k];
    acc[0][0]=fmaf(a0,b0.x,acc[0][0]); acc[0][1]=fmaf(a0,b0.y,acc[0][1]);
    acc[0][2]=fmaf(a0,b0.z,acc[0][2]); acc[0][3]=fmaf(a0,b0.w,acc[0][3]);
    acc[0][4]=fmaf(a0,b1.x,acc[0][4]); acc[0][5]=fmaf(a0,b1.y,acc[0][5]);
    acc[0][6]=fmaf(a0,b1.z,acc[0][6]); acc[0][7]=fmaf(a0,b1.w,acc[0][7]);
    acc[1][0]=fmaf(a1,b0.x,acc[1][0]); acc[1][1]=fmaf(a1,b0.y,acc[1][1]);
    acc[1][2]=fmaf(a1,b0.z,acc[1][2]); acc[1][3]=fmaf(a1,b0.w,acc[1][3]);
    acc[1][4]=fmaf(a1,b1.x,acc[1][4]); acc[1][5]=fmaf(a1,b1.y,acc[1][5]);
    acc[1][6]=fmaf(a1,b1.z,acc[1][6]); acc[1][7]=fmaf(a1,b1.w,acc[1][7]);
    acc[2][0]=fmaf(a2,b0.x,acc[2][0]); acc[2][1]=fmaf(a2,b0.y,acc[2][1]);
    acc[2][2]=fmaf(a2,b0.z,acc[2][2]); acc[2][3]=fmaf(a2,b0.w,acc[2][3]);
    acc[2][4]=fmaf(a2,b1.x,acc[2][4]); acc[2][5]=fmaf(a2,b1.y,acc[2][5]);
    acc[2][6]=fmaf(a2,b1.z,acc[2][6]); acc[2][7]=fmaf(a2,b1.w,acc[2][7]);
    acc[3][0]=fmaf(a3,b0.x,acc[3][0]); acc[3][1]=fmaf(a3,b0.y,acc[3][1]);
    acc[3][2]=fmaf(a3,b0.z,acc[3][2]); acc[3][3]=fmaf(a3,b0.w,acc[3][3]);
    acc[3][4]=fmaf(a3,b1.x,acc[3][4]); acc[3][5]=fmaf(a3,b1.y,acc[3][5]);
    acc[3][6]=fmaf(a3,b1.z,acc[3][6]); acc[3][7]=fmaf(a3,b1.w,acc[3][7]);
  }
  #pragma unroll
  for(int r=0;r<4;r++){
    int gr = row0 + ty*4 + r;
    if(gr < NN){
      us8_t o;
      #pragma unroll
      for(int j=0;j<8;j++) o[j] = f2us(fmaxf(acc[r][j] + bs[tx*8+j], 0.0f));
      *(us8_t*)((unsigned short*)f + (size_t)gr*128 + tx*8) = o;
    }
  }
}

// ---------------- fc2: [NN x 128] @ [128 x 32] + b -> out ----------------
__global__ void __launch_bounds__(256) k_fc2(const bf16* __restrict__ f,
                                             const float* __restrict__ Wc,
                                             const int* __restrict__ flag,
                                             void* __restrict__ outv){
  __shared__ float W2s[128*32];
  __shared__ float fs[64][132];
  __shared__ float bs[32];
  int tid = threadIdx.x;
  for(int j=tid; j<4096; j+=256) W2s[j] = Wc[FW2F+j];
  if(tid < 32) bs[tid] = Wc[FB2F+tid];
  int row0 = blockIdx.x*64;
  for(int ch = tid; ch < 1024; ch += 256){
    int r = ch>>4, c8 = (ch&15)*8, gr = row0 + r;
    float fv[8];
    if(gr < NN){
      us8_t v = *(const us8_t*)((const unsigned short*)f + (size_t)gr*128 + c8);
      #pragma unroll
      for(int j=0;j<8;j++) fv[j] = us2f(v[j]);
    } else {
      #pragma unroll
      for(int j=0;j<8;j++) fv[j] = 0.0f;
    }
    *(float4*)&fs[r][c8]   = make_float4(fv[0],fv[1],fv[2],fv[3]);
    *(float4*)&fs[r][c8+4] = make_float4(fv[4],fv[5],fv[6],fv[7]);
  }
  __syncthreads();
  int ty = tid>>3, tx = tid&7;
  float acc[2][4] = {{0}};
  #pragma unroll 8
  for(int k=0;k<128;k++){
    float4 b4 = *(const float4*)&W2s[k*32 + tx*4];
    float a0 = fs[ty*2+0][k], a1 = fs[ty*2+1][k];
    acc[0][0]=fmaf(a0,b4.x,acc[0][0]); acc[0][1]=fmaf(a0,b4.y,acc[0][1]);
    acc[0][2]=fmaf(a0,b4.z,acc[0][2]); acc[0][3]=fmaf(a0,b4.w,acc[0][3]);
    acc[1][0]=fmaf(a1,b4.x,acc[1][0]); acc[1][1]=fmaf(a1,b4.y,acc[1][1]);
    acc[1][2]=fmaf(a1,b4.z,acc[1][2]); acc[1][3]=fmaf(a1,b4.w,acc[1][3]);
  }
  int fl = *flag;
  #pragma unroll
  for(int r=0;r<2;r++){
    int gr = row0 + ty*2 + r;
    if(gr < NN){
      float o0 = acc[r][0]+bs[tx*4+0], o1 = acc[r][1]+bs[tx*4+1];
      float o2 = acc[r][2]+bs[tx*4+2], o3 = acc[r][3]+bs[tx*4+3];
      if(fl){
        *(float4*)((float*)outv + (size_t)gr*32 + tx*4) = make_float4(o0,o1,o2,o3);
      } else {
        unsigned lo = f2us(o0) | ((unsigned)f2us(o1)<<16);
        unsigned hi = f2us(o2) | ((unsigned)f2us(o3)<<16);
        uint2 o; o.x = lo; o.y = hi;
        *(uint2*)((unsigned short*)outv + (size_t)gr*32 + tx*4) = o;
      }
    }
  }
}

extern "C" void kernel_launch(void* const* d_in, const int* in_sizes, int n_in,
                              void* d_out, int out_size, void* d_ws, size_t ws_size,
                              hipStream_t stream){
  const void* x   = d_in[0];
  const int*  ei  = (const int*)d_in[1];
  const int* srcI = ei;        // edge_index[0]
  const int* dstI = ei + NE;   // edge_index[1]

  // workspace layout (bytes); total ~60 MB
  char*   base   = (char*)d_ws;
  int*    flag   = (int*)   (base + 0);          // 256
  float*  Wc     = (float*) (base + 256);        // 83840 -> 84096
  int*    bstart = (int*)   (base + 84224);      // (NBUK+1)*4 = 6256
  int*    cnt    = (int*)   (base + 90624);      // CNTSZ*4 = 306348
  float*  dinv   = (float*) (base + 397056);     // 400000
  int*    epk    = (int*)   (base + 797184);     // 6400000
  float2* xd     = (float2*)(base + 7197440);    // 800000
  float2* y      = (float2*)(base + 7997440);    // 800000
  bf16*   s      = (bf16*)  (base + 8797440);    // 12800000
  bf16*   h      = (bf16*)  (base + 21597440);   // 12800000
  bf16*   f      = (bf16*)  (base + 34397440);   // 25600000 -> ends 59997440

  k_sniff<<<1, 1024, 0, stream>>>((const unsigned short*)x, flag);
  k_convert_w<<<1, 256, 0, stream>>>(d_in[2], d_in[3], d_in[4], d_in[5], d_in[6],
                                     d_in[7], d_in[8], d_in[9], d_in[10], d_in[11],
                                     flag, Wc);

  // bucket-CSR build (64-node dst buckets, packed (src<<6)|dst_local)
  k_bhist <<<NBB, 256, 0, stream>>>(dstI, cnt);
  k_bscan <<<1, 1024, 0, stream>>>(cnt, bstart);
  k_bplace<<<NBB, 256, 0, stream>>>(srcI, dstI, cnt, epk);
  k_degb  <<<NBUK, 256, 0, stream>>>(bstart, epk, dinv);

  // layer 1 (2 -> 64): propagate x first (8B gathers), then transform
  k_xd         <<<(NN+255)/256, 256, 0, stream>>>(x, flag, dinv, xd);
  k_prop_xb    <<<NBUK, 256, 0, stream>>>(bstart, epk, xd, y);
  k_transform1b<<<NN*8/256, 256, 0, stream>>>(y, Wc, dinv, h);

  // layer 2 (64 -> 64)
  k_transform64<<<(NN+63)/64, 256, 0, stream>>>(h, Wc+W2F, dinv, s);
  k_agg        <<<NBUK, 256, 0, stream>>>(bstart, epk, s, dinv, Wc+B2F, h);

  // layer 3 (64 -> 64)
  k_transform64<<<(NN+63)/64, 256, 0, stream>>>(h, Wc+W3F, dinv, s);
  k_agg        <<<NBUK, 256, 0, stream>>>(bstart, epk, s, dinv, Wc+B3F, h);

  // fc1 + fc2 (register-tiled GEMMs)
  k_fc1<<<(NN+63)/64, 256, 0, stream>>>(h, Wc, f);
  k_fc2<<<(NN+63)/64, 256, 0, stream>>>(f, Wc, flag, d_out);
}

// Round 8
// 641.216 us; speedup vs baseline: 2.7125x; 2.7125x over previous
//
#include <hip/hip_runtime.h>
#include <hip/hip_bf16.h>

#define NN 100000
#define NE 1600000
#define NBUK 1563          // ceil(NN/64) 64-node dst buckets
#define NBB  49            // histogram blocks (32768 edges each)
#define BATCH 32768
#define CNTSZ (NBUK*NBB)   // 76587
#define CHUNK 75           // 75*1024 >= CNTSZ

using bf16 = __hip_bfloat16;
typedef unsigned short us8_t __attribute__((ext_vector_type(8)));
static __device__ __forceinline__ float b2f(bf16 v){ return __bfloat162float(v); }
static __device__ __forceinline__ bf16 f2b(float v){ return __float2bfloat16(v); }
static __device__ __forceinline__ float us2f(unsigned u){
  unsigned x = u<<16; float f; __builtin_memcpy(&f,&x,4); return f;
}
static __device__ __forceinline__ unsigned short f2us(float v){
  bf16 b = f2b(v); unsigned short u; __builtin_memcpy(&u,&b,2); return u;
}

// canonical f32 weight-pool offsets (floats)
#define W1F   0
#define B1F   128
#define W2F   192
#define B2F   4288
#define W3F   4352
#define B3F   8448
#define FW1F  8512
#define FB1F  16704
#define FW2F  16832
#define FB2F  20928
#define WTOT  20960

// ---- dtype sniff (f32 vs bf16 storage) ----
__global__ void k_sniff(const unsigned short* __restrict__ xr, int* flag){
  __shared__ int found;
  if(threadIdx.x==0) found = 0;
  __syncthreads();
  int loc = 0;
  for(int i=threadIdx.x*2; i<200000; i+=2048){
    unsigned e = (xr[i]>>7)&0xFF;
    if(e==0xFFu || e==0u) loc = 1;
  }
  if(loc) found = 1;
  __syncthreads();
  if(threadIdx.x==0) *flag = found;   // 1 = f32 storage, 0 = bf16 storage
}

__global__ void k_convert_w(const void* p0,const void* p1,const void* p2,const void* p3,
                            const void* p4,const void* p5,const void* p6,const void* p7,
                            const void* p8,const void* p9,
                            const int* __restrict__ flag, float* __restrict__ Wc){
  const void* ps[10] = {p0,p1,p2,p3,p4,p5,p6,p7,p8,p9};
  const int off[11] = {W1F,B1F,W2F,B2F,W3F,B3F,FW1F,FB1F,FW2F,FB2F,WTOT};
  int f = *flag;
  for(int t=threadIdx.x; t<WTOT; t+=256){
    int seg = 0;
    while(off[seg+1] <= t) seg++;
    int j = t - off[seg];
    Wc[t] = f ? ((const float*)ps[seg])[j] : b2f(((const bf16*)ps[seg])[j]);
  }
}

// ---------------- bucket-CSR build ----------------
__global__ void k_bhist(const int* __restrict__ dst, int* __restrict__ cnt){
  __shared__ int hist[NBUK];
  for(int j=threadIdx.x; j<NBUK; j+=256) hist[j] = 0;
  __syncthreads();
  int e0 = blockIdx.x*BATCH;
  int e1 = min(NE, e0+BATCH);
  for(int e=e0+threadIdx.x; e<e1; e+=256) atomicAdd(&hist[dst[e]>>6], 1);
  __syncthreads();
  for(int j=threadIdx.x; j<NBUK; j+=256) cnt[j*NBB + blockIdx.x] = hist[j];
}
__global__ void k_bscan(int* __restrict__ cnt, int* __restrict__ bucketStart){
  __shared__ int part[1024];
  int t = threadIdx.x;
  int lo = t*CHUNK, hi = min(CNTSZ, lo+CHUNK);
  int sum = 0;
  for(int j=lo; j<hi; j++) sum += cnt[j];
  part[t] = sum; __syncthreads();
  for(int off=1; off<1024; off<<=1){
    int v = (t>=off) ? part[t-off] : 0;
    __syncthreads();
    part[t] += v;
    __syncthreads();
  }
  int run = (t>0) ? part[t-1] : 0;
  for(int j=lo; j<hi; j++){
    int c = cnt[j];
    cnt[j] = run;
    if(j % NBB == 0) bucketStart[j/NBB] = run;
    run += c;
  }
  if(t==0) bucketStart[NBUK] = NE;
}
__global__ void k_bplace(const int* __restrict__ src, const int* __restrict__ dst,
                         const int* __restrict__ cnt, int* __restrict__ epk){
  __shared__ int cur[NBUK];
  for(int j=threadIdx.x; j<NBUK; j+=256) cur[j] = cnt[j*NBB + blockIdx.x];
  __syncthreads();
  int e0 = blockIdx.x*BATCH, e1 = min(NE, e0+BATCH);
  for(int e=e0+threadIdx.x; e<e1; e+=256){
    int d = dst[e];
    int pos = atomicAdd(&cur[d>>6], 1);
    epk[pos] = (src[e]<<6) | (d&63);
  }
}
// in-bucket counting sort -> exact node-grouped CSR (rowptr, srcS) + dinv.
// All scattered writes confined to this block's 4KB bucket window.
__global__ void k_bsort(const int* __restrict__ bucketStart, const int* __restrict__ epk,
                        int* __restrict__ srcS, int* __restrict__ rowptr,
                        float* __restrict__ dinv){
  __shared__ int hist[64], excl[64], cur[64];
  int tid = threadIdx.x;
  if(tid < 64) hist[tid] = 0;
  __syncthreads();
  int b = blockIdx.x, beg = bucketStart[b], end = bucketStart[b+1];
  for(int p=beg+tid; p<end; p+=256) atomicAdd(&hist[epk[p]&63], 1);
  __syncthreads();
  if(tid == 0){
    int run = 0;
    for(int j=0;j<64;j++){ excl[j] = run; run += hist[j]; }
  }
  __syncthreads();
  if(tid < 64){
    int g = b*64 + tid;
    if(g < NN){
      rowptr[g] = beg + excl[tid];
      dinv[g]   = rsqrtf((float)(hist[tid] + 1));   // +1 self-loop
    }
    cur[tid] = excl[tid];
  }
  if(b == 0 && tid == 0) rowptr[NN] = NE;
  __syncthreads();
  for(int p=beg+tid; p<end; p+=256){
    int pk = epk[p];
    int pos = atomicAdd(&cur[pk&63], 1);
    srcS[beg+pos] = pk>>6;
  }
}

// ---------------- layer 1 (propagate-then-transform; X has 2 channels) ----------------
__global__ void k_xd(const void* __restrict__ xv, const int* __restrict__ flag,
                     const float* __restrict__ dinv, float2* __restrict__ xd){
  int i = blockIdx.x*256 + threadIdx.x;
  if(i >= NN) return;
  float x0, x1;
  if(*flag){ float2 p = ((const float2*)xv)[i]; x0=p.x; x1=p.y; }
  else     { const bf16* xp=(const bf16*)xv; x0=b2f(xp[2*i]); x1=b2f(xp[2*i+1]); }
  float d = dinv[i];
  xd[i] = make_float2(x0*d, x1*d);
}
__global__ void k_prop_x(const int* __restrict__ rowptr, const int* __restrict__ srcS,
                         const float2* __restrict__ xd, float2* __restrict__ y){
  int i = blockIdx.x*256 + threadIdx.x;
  if(i >= NN) return;
  int beg = rowptr[i], end = rowptr[i+1];
  float2 self = xd[i];
  float ax0 = self.x, ay0 = self.y;
  float ax1=0,ay1=0, ax2=0,ay2=0, ax3=0,ay3=0;
  int p = beg;
  for(; p+4 <= end; p += 4){
    int s0=srcS[p], s1=srcS[p+1], s2=srcS[p+2], s3=srcS[p+3];
    float2 v0=xd[s0], v1=xd[s1], v2=xd[s2], v3=xd[s3];
    ax0+=v0.x; ay0+=v0.y; ax1+=v1.x; ay1+=v1.y;
    ax2+=v2.x; ay2+=v2.y; ax3+=v3.x; ay3+=v3.y;
  }
  for(; p<end; p++){ float2 v=xd[srcS[p]]; ax0+=v.x; ay0+=v.y; }
  y[i] = make_float2((ax0+ax1)+(ax2+ax3), (ay0+ay1)+(ay2+ay3));
}
__global__ void k_transform1b(const float2* __restrict__ y, const float* __restrict__ Wc,
                              const float* __restrict__ dinv, bf16* __restrict__ h){
  __shared__ float W1s[128];
  __shared__ float bs[64];
  if(threadIdx.x < 128) W1s[threadIdx.x] = Wc[W1F + threadIdx.x];
  if(threadIdx.x < 64)  bs[threadIdx.x]  = Wc[B1F + threadIdx.x];
  __syncthreads();
  int t = blockIdx.x*256 + threadIdx.x;   // grid NN*8 threads
  int i = t>>3, g = t&7;
  float2 yv = y[i];
  float d = dinv[i];
  us8_t o;
  #pragma unroll
  for(int j=0;j<8;j++){
    int c = g*8+j;
    o[j] = f2us(fmaxf(d*(yv.x*W1s[c] + yv.y*W1s[64+c]) + bs[c], 0.0f));
  }
  *(us8_t*)((unsigned short*)h + (size_t)i*64 + g*8) = o;
}

// ---------------- 64->64 transform (LDS-tiled GEMM, 4x4 tile/thread) ----------------
__global__ void __launch_bounds__(256) k_transform64(
    const bf16* __restrict__ h, const float* __restrict__ W,
    const float* __restrict__ dinv, bf16* __restrict__ s){
  __shared__ float Ws[64*64];
  __shared__ float hs[64][68];
  __shared__ float dl[64];
  int tid = threadIdx.x;
  for(int j=tid; j<4096; j+=256) Ws[j] = W[j];
  int row0 = blockIdx.x*64;
  if(tid < 64){ int r = row0+tid; dl[tid] = (r<NN)? dinv[r] : 0.0f; }
  for(int ch = tid; ch < 512; ch += 256){
    int r = ch>>3, c8 = (ch&7)*8;
    int gr = row0 + r;
    float f[8];
    if(gr < NN){
      us8_t v = *(const us8_t*)((const unsigned short*)h + (size_t)gr*64 + c8);
      #pragma unroll
      for(int j=0;j<8;j++) f[j] = us2f(v[j]);
    } else {
      #pragma unroll
      for(int j=0;j<8;j++) f[j] = 0.0f;
    }
    *(float4*)&hs[r][c8]   = make_float4(f[0],f[1],f[2],f[3]);
    *(float4*)&hs[r][c8+4] = make_float4(f[4],f[5],f[6],f[7]);
  }
  __syncthreads();
  int ty = tid>>4, tx = tid&15;
  float acc[4][4] = {{0}};
  #pragma unroll 8
  for(int k=0;k<64;k++){
    float4 b4 = *(const float4*)&Ws[k*64 + tx*4];
    float a0 = hs[ty*4+0][k];
    float a1 = hs[ty*4+1][k];
    float a2 = hs[ty*4+2][k];
    float a3 = hs[ty*4+3][k];
    acc[0][0] = fmaf(a0,b4.x,acc[0][0]); acc[0][1] = fmaf(a0,b4.y,acc[0][1]);
    acc[0][2] = fmaf(a0,b4.z,acc[0][2]); acc[0][3] = fmaf(a0,b4.w,acc[0][3]);
    acc[1][0] = fmaf(a1,b4.x,acc[1][0]); acc[1][1] = fmaf(a1,b4.y,acc[1][1]);
    acc[1][2] = fmaf(a1,b4.z,acc[1][2]); acc[1][3] = fmaf(a1,b4.w,acc[1][3]);
    acc[2][0] = fmaf(a2,b4.x,acc[2][0]); acc[2][1] = fmaf(a2,b4.y,acc[2][1]);
    acc[2][2] = fmaf(a2,b4.z,acc[2][2]); acc[2][3] = fmaf(a2,b4.w,acc[2][3]);
    acc[3][0] = fmaf(a3,b4.x,acc[3][0]); acc[3][1] = fmaf(a3,b4.y,acc[3][1]);
    acc[3][2] = fmaf(a3,b4.z,acc[3][2]); acc[3][3] = fmaf(a3,b4.w,acc[3][3]);
  }
  #pragma unroll
  for(int rr=0; rr<4; rr++){
    int r = row0 + ty*4 + rr;
    if(r < NN){
      float dv = dl[ty*4+rr];
      unsigned lo = f2us(acc[rr][0]*dv) | ((unsigned)f2us(acc[rr][1]*dv) << 16);
      unsigned hi = f2us(acc[rr][2]*dv) | ((unsigned)f2us(acc[rr][3]*dv) << 16);
      uint2 o; o.x = lo; o.y = hi;
      *(uint2*)((unsigned short*)s + (size_t)r*64 + tx*4) = o;
    }
  }
}

// ---------------- CSR aggregate + finalize: wave per node, 4 edges per wave-load ----------------
// lane: g = lane>>4 (edge slot), q = lane&15 (channel quad). uint2 = 4 bf16 channels.
__global__ void __launch_bounds__(256) k_aggregate(
    const int* __restrict__ rowptr, const int* __restrict__ srcS,
    const bf16* __restrict__ s, const float* __restrict__ dinv,
    const float* __restrict__ bias, bf16* __restrict__ h){
  int wave = threadIdx.x>>6, lane = threadIdx.x&63;
  int i = blockIdx.x*4 + wave;            // grid = NN/4 = 25000 blocks
  if(i >= NN) return;
  int beg = rowptr[i], end = rowptr[i+1];
  int g = lane>>4, q = lane&15;
  const unsigned short* sp = (const unsigned short*)s;
  float a[4][4] = {{0}};
  int p = beg;
  for(; p+16 <= end; p += 16){            // 16 edges in flight
    #pragma unroll
    for(int t=0;t<4;t++){
      int e = srcS[p + t*4 + g];
      uint2 v = *(const uint2*)(sp + (size_t)e*64 + q*4);
      a[t][0] += us2f(v.x & 0xffffu); a[t][1] += us2f(v.x >> 16);
      a[t][2] += us2f(v.y & 0xffffu); a[t][3] += us2f(v.y >> 16);
    }
  }
  for(; p+4 <= end; p += 4){
    int e = srcS[p + g];
    uint2 v = *(const uint2*)(sp + (size_t)e*64 + q*4);
    a[0][0] += us2f(v.x & 0xffffu); a[0][1] += us2f(v.x >> 16);
    a[0][2] += us2f(v.y & 0xffffu); a[0][3] += us2f(v.y >> 16);
  }
  if(g == 0){                             // tail (<4 edges), counted once
    for(; p < end; p++){
      int e = srcS[p];
      uint2 v = *(const uint2*)(sp + (size_t)e*64 + q*4);
      a[1][0] += us2f(v.x & 0xffffu); a[1][1] += us2f(v.x >> 16);
      a[1][2] += us2f(v.y & 0xffffu); a[1][3] += us2f(v.y >> 16);
    }
  }
  float c0 = (a[0][0]+a[1][0])+(a[2][0]+a[3][0]);
  float c1 = (a[0][1]+a[1][1])+(a[2][1]+a[3][1]);
  float c2 = (a[0][2]+a[1][2])+(a[2][2]+a[3][2]);
  float c3 = (a[0][3]+a[1][3])+(a[2][3]+a[3][3]);
  // reduce across the 4 edge slots (lane bits 4,5)
  c0 += __shfl_xor(c0,16,64); c0 += __shfl_xor(c0,32,64);
  c1 += __shfl_xor(c1,16,64); c1 += __shfl_xor(c1,32,64);
  c2 += __shfl_xor(c2,16,64); c2 += __shfl_xor(c2,32,64);
  c3 += __shfl_xor(c3,16,64); c3 += __shfl_xor(c3,32,64);
  // self-loop + finalize
  uint2 sv = *(const uint2*)(sp + (size_t)i*64 + q*4);
  c0 += us2f(sv.x & 0xffffu); c1 += us2f(sv.x >> 16);
  c2 += us2f(sv.y & 0xffffu); c3 += us2f(sv.y >> 16);
  float dv = dinv[i];
  float4 bv = *(const float4*)&bias[q*4];
  c0 = fmaxf(fmaf(dv, c0, bv.x), 0.0f);
  c1 = fmaxf(fmaf(dv, c1, bv.y), 0.0f);
  c2 = fmaxf(fmaf(dv, c2, bv.z), 0.0f);
  c3 = fmaxf(fmaf(dv, c3, bv.w), 0.0f);
  if(g == 0){                             // lanes 0..15 store 128B contiguous
    unsigned lo = f2us(c0) | ((unsigned)f2us(c1) << 16);
    unsigned hi = f2us(c2) | ((unsigned)f2us(c3) << 16);
    uint2 o; o.x = lo; o.y = hi;
    *(uint2*)((unsigned short*)h + (size_t)i*64 + q*4) = o;
  }
}

// ---------------- fc1: [NN x 64] @ [64 x 128] + b, relu -> f (bf16) ----------------
__global__ void __launch_bounds__(256) k_fc1(const bf16* __restrict__ h,
                                             const float* __restrict__ Wc,
                                             bf16* __restrict__ f){
  __shared__ float W1s[64*128];
  __shared__ float hs[64][68];
  __shared__ float bs[128];
  int tid = threadIdx.x;
  for(int j=tid; j<8192; j+=256) W1s[j] = Wc[FW1F+j];
  if(tid < 128) bs[tid] = Wc[FB1F+tid];
  int row0 = blockIdx.x*64;
  for(int ch = tid; ch < 512; ch += 256){
    int r = ch>>3, c8 = (ch&7)*8, gr = row0 + r;
    float fv[8];
    if(gr < NN){
      us8_t v = *(const us8_t*)((const unsigned short*)h + (size_t)gr*64 + c8);
      #pragma unroll
      for(int j=0;j<8;j++) fv[j] = us2f(v[j]);
    } else {
      #pragma unroll
      for(int j=0;j<8;j++) fv[j] = 0.0f;
    }
    *(float4*)&hs[r][c8]   = make_float4(fv[0],fv[1],fv[2],fv[3]);
    *(float4*)&hs[r][c8+4] = make_float4(fv[4],fv[5],fv[6],fv[7]);
  }
  __syncthreads();
  int ty = tid>>4, tx = tid&15;
  float acc[4][8] = {{0}};
  #pragma unroll 4
  for(int k=0;k<64;k++){
    float4 b0 = *(const float4*)&W1s[k*128 + tx*8];
    float4 b1 = *(const float4*)&W1s[k*128 + tx*8 + 4];
    float a0 = hs[ty*4+0][k], a1 = hs[ty*4+1][k];
    float a2 = hs[ty*4+2][k], a3 = hs[ty*4+3][k];
    acc[0][0]=fmaf(a0,b0.x,acc[0][0]); acc[0][1]=fmaf(a0,b0.y,acc[0][1]);
    acc[0][2]=fmaf(a0,b0.z,acc[0][2]); acc[0][3]=fmaf(a0,b0.w,acc[0][3]);
    acc[0][4]=fmaf(a0,b1.x,acc[0][4]); acc[0][5]=fmaf(a0,b1.y,acc[0][5]);
    acc[0][6]=fmaf(a0,b1.z,acc[0][6]); acc[0][7]=fmaf(a0,b1.w,acc[0][7]);
    acc[1][0]=fmaf(a1,b0.x,acc[1][0]); acc[1][1]=fmaf(a1,b0.y,acc[1][1]);
    acc[1][2]=fmaf(a1,b0.z,acc[1][2]); acc[1][3]=fmaf(a1,b0.w,acc[1][3]);
    acc[1][4]=fmaf(a1,b1.x,acc[1][4]); acc[1][5]=fmaf(a1,b1.y,acc[1][5]);
    acc[1][6]=fmaf(a1,b1.z,acc[1][6]); acc[1][7]=fmaf(a1,b1.w,acc[1][7]);
    acc[2][0]=fmaf(a2,b0.x,acc[2][0]); acc[2][1]=fmaf(a2,b0.y,acc[2][1]);
    acc[2][2]=fmaf(a2,b0.z,acc[2][2]); acc[2][3]=fmaf(a2,b0.w,acc[2][3]);
    acc[2][4]=fmaf(a2,b1.x,acc[2][4]); acc[2][5]=fmaf(a2,b1.y,acc[2][5]);
    acc[2][6]=fmaf(a2,b1.z,acc[2][6]); acc[2][7]=fmaf(a2,b1.w,acc[2][7]);
    acc[3][0]=fmaf(a3,b0.x,acc[3][0]); acc[3][1]=fmaf(a3,b0.y,acc[3][1]);
    acc[3][2]=fmaf(a3,b0.z,acc[3][2]); acc[3][3]=fmaf(a3,b0.w,acc[3][3]);
    acc[3][4]=fmaf(a3,b1.x,acc[3][4]); acc[3][5]=fmaf(a3,b1.y,acc[3][5]);
    acc[3][6]=fmaf(a3,b1.z,acc[3][6]); acc[3][7]=fmaf(a3,b1.w,acc[3][7]);
  }
  #pragma unroll
  for(int r=0;r<4;r++){
    int gr = row0 + ty*4 + r;
    if(gr < NN){
      us8_t o;
      #pragma unroll
      for(int j=0;j<8;j++) o[j] = f2us(fmaxf(acc[r][j] + bs[tx*8+j], 0.0f));
      *(us8_t*)((unsigned short*)f + (size_t)gr*128 + tx*8) = o;
    }
  }
}

// ---------------- fc2: [NN x 128] @ [128 x 32] + b -> out ----------------
__global__ void __launch_bounds__(256) k_fc2(const bf16* __restrict__ f,
                                             const float* __restrict__ Wc,
                                             const int* __restrict__ flag,
                                             void* __restrict__ outv){
  __shared__ float W2s[128*32];
  __shared__ float fs[64][132];
  __shared__ float bs[32];
  int tid = threadIdx.x;
  for(int j=tid; j<4096; j+=256) W2s[j] = Wc[FW2F+j];
  if(tid < 32) bs[tid] = Wc[FB2F+tid];
  int row0 = blockIdx.x*64;
  for(int ch = tid; ch < 1024; ch += 256){
    int r = ch>>4, c8 = (ch&15)*8, gr = row0 + r;
    float fv[8];
    if(gr < NN){
      us8_t v = *(const us8_t*)((const unsigned short*)f + (size_t)gr*128 + c8);
      #pragma unroll
      for(int j=0;j<8;j++) fv[j] = us2f(v[j]);
    } else {
      #pragma unroll
      for(int j=0;j<8;j++) fv[j] = 0.0f;
    }
    *(float4*)&fs[r][c8]   = make_float4(fv[0],fv[1],fv[2],fv[3]);
    *(float4*)&fs[r][c8+4] = make_float4(fv[4],fv[5],fv[6],fv[7]);
  }
  __syncthreads();
  int ty = tid>>3, tx = tid&7;
  float acc[2][4] = {{0}};
  #pragma unroll 8
  for(int k=0;k<128;k++){
    float4 b4 = *(const float4*)&W2s[k*32 + tx*4];
    float a0 = fs[ty*2+0][k], a1 = fs[ty*2+1][k];
    acc[0][0]=fmaf(a0,b4.x,acc[0][0]); acc[0][1]=fmaf(a0,b4.y,acc[0][1]);
    acc[0][2]=fmaf(a0,b4.z,acc[0][2]); acc[0][3]=fmaf(a0,b4.w,acc[0][3]);
    acc[1][0]=fmaf(a1,b4.x,acc[1][0]); acc[1][1]=fmaf(a1,b4.y,acc[1][1]);
    acc[1][2]=fmaf(a1,b4.z,acc[1][2]); acc[1][3]=fmaf(a1,b4.w,acc[1][3]);
  }
  int fl = *flag;
  #pragma unroll
  for(int r=0;r<2;r++){
    int gr = row0 + ty*2 + r;
    if(gr < NN){
      float o0 = acc[r][0]+bs[tx*4+0], o1 = acc[r][1]+bs[tx*4+1];
      float o2 = acc[r][2]+bs[tx*4+2], o3 = acc[r][3]+bs[tx*4+3];
      if(fl){
        *(float4*)((float*)outv + (size_t)gr*32 + tx*4) = make_float4(o0,o1,o2,o3);
      } else {
        unsigned lo = f2us(o0) | ((unsigned)f2us(o1)<<16);
        unsigned hi = f2us(o2) | ((unsigned)f2us(o3)<<16);
        uint2 o; o.x = lo; o.y = hi;
        *(uint2*)((unsigned short*)outv + (size_t)gr*32 + tx*4) = o;
      }
    }
  }
}

extern "C" void kernel_launch(void* const* d_in, const int* in_sizes, int n_in,
                              void* d_out, int out_size, void* d_ws, size_t ws_size,
                              hipStream_t stream){
  const void* x   = d_in[0];
  const int*  ei  = (const int*)d_in[1];
  const int* srcI = ei;        // edge_index[0]
  const int* dstI = ei + NE;   // edge_index[1]

  // workspace layout (bytes); total ~67 MB
  char*   base   = (char*)d_ws;
  int*    flag   = (int*)   (base + 0);          // 256
  float*  Wc     = (float*) (base + 256);        // 83840 -> 84096
  int*    bstart = (int*)   (base + 84224);      // 6256
  int*    cnt    = (int*)   (base + 90624);      // 306348
  float*  dinv   = (float*) (base + 397056);     // 400000
  int*    rowptr = (int*)   (base + 797056);     // 400004
  int*    epk    = (int*)   (base + 1197184);    // 6400000
  int*    srcS   = (int*)   (base + 7597184);    // 6400000
  float2* xd     = (float2*)(base + 13997184);   // 800000
  float2* y      = (float2*)(base + 14797184);   // 800000
  bf16*   s      = (bf16*)  (base + 15597184);   // 12800000
  bf16*   h      = (bf16*)  (base + 28397184);   // 12800000
  bf16*   f      = (bf16*)  (base + 41197184);   // 25600000 -> ends 66797184

  k_sniff<<<1, 1024, 0, stream>>>((const unsigned short*)x, flag);
  k_convert_w<<<1, 256, 0, stream>>>(d_in[2], d_in[3], d_in[4], d_in[5], d_in[6],
                                     d_in[7], d_in[8], d_in[9], d_in[10], d_in[11],
                                     flag, Wc);

  // bucket-grouped build, then in-bucket counting sort -> exact CSR
  k_bhist <<<NBB, 256, 0, stream>>>(dstI, cnt);
  k_bscan <<<1, 1024, 0, stream>>>(cnt, bstart);
  k_bplace<<<NBB, 256, 0, stream>>>(srcI, dstI, cnt, epk);
  k_bsort <<<NBUK, 256, 0, stream>>>(bstart, epk, srcS, rowptr, dinv);

  // layer 1 (2 -> 64): propagate x first (8B gathers), then transform
  k_xd         <<<(NN+255)/256, 256, 0, stream>>>(x, flag, dinv, xd);
  k_prop_x     <<<(NN+255)/256, 256, 0, stream>>>(rowptr, srcS, xd, y);
  k_transform1b<<<NN*8/256, 256, 0, stream>>>(y, Wc, dinv, h);

  // layer 2 (64 -> 64)
  k_transform64<<<(NN+63)/64, 256, 0, stream>>>(h, Wc+W2F, dinv, s);
  k_aggregate  <<<NN/4, 256, 0, stream>>>(rowptr, srcS, s, dinv, Wc+B2F, h);

  // layer 3 (64 -> 64)
  k_transform64<<<(NN+63)/64, 256, 0, stream>>>(h, Wc+W3F, dinv, s);
  k_aggregate  <<<NN/4, 256, 0, stream>>>(rowptr, srcS, s, dinv, Wc+B3F, h);

  // fc1 + fc2 (register-tiled GEMMs)
  k_fc1<<<(NN+63)/64, 256, 0, stream>>>(h, Wc, f);
  k_fc2<<<(NN+63)/64, 256, 0, stream>>>(f, Wc, flag, d_out);
}

// Round 9
// 491.938 us; speedup vs baseline: 3.5357x; 1.3034x over previous
//
#include <hip/hip_runtime.h>
#include <hip/hip_bf16.h>

#define NN 100000
#define NE 1600000
#define NBUK 1563          // ceil(NN/64) 64-node dst buckets
#define NBB  49            // histogram blocks (32768 edges each)
#define BATCH 32768
#define CNTSZ (NBUK*NBB)   // 76587
#define SCANB 75           // ceil(CNTSZ/1024)

using bf16 = __hip_bfloat16;
typedef unsigned short us8_t __attribute__((ext_vector_type(8)));
static __device__ __forceinline__ float b2f(bf16 v){ return __bfloat162float(v); }
static __device__ __forceinline__ bf16 f2b(float v){ return __float2bfloat16(v); }
static __device__ __forceinline__ float us2f(unsigned u){
  unsigned x = u<<16; float f; __builtin_memcpy(&f,&x,4); return f;
}
static __device__ __forceinline__ unsigned short f2us(float v){
  bf16 b = f2b(v); unsigned short u; __builtin_memcpy(&u,&b,2); return u;
}

// canonical f32 weight-pool offsets (floats)
#define W1F   0
#define B1F   128
#define W2F   192
#define B2F   4288
#define W3F   4352
#define B3F   8448
#define FW1F  8512
#define FB1F  16704
#define FW2F  16832
#define FB2F  20928
#define WTOT  20960

// ---- dtype sniff (f32 vs bf16 storage) ----
__global__ void k_sniff(const unsigned short* __restrict__ xr, int* flag){
  __shared__ int found;
  if(threadIdx.x==0) found = 0;
  __syncthreads();
  int loc = 0;
  for(int i=threadIdx.x*2; i<200000; i+=2048){
    unsigned e = (xr[i]>>7)&0xFF;
    if(e==0xFFu || e==0u) loc = 1;
  }
  if(loc) found = 1;
  __syncthreads();
  if(threadIdx.x==0) *flag = found;   // 1 = f32 storage, 0 = bf16 storage
}

__global__ void k_convert_w(const void* p0,const void* p1,const void* p2,const void* p3,
                            const void* p4,const void* p5,const void* p6,const void* p7,
                            const void* p8,const void* p9,
                            const int* __restrict__ flag, float* __restrict__ Wc){
  const void* ps[10] = {p0,p1,p2,p3,p4,p5,p6,p7,p8,p9};
  const int off[11] = {W1F,B1F,W2F,B2F,W3F,B3F,FW1F,FB1F,FW2F,FB2F,WTOT};
  int f = *flag;
  for(int t=threadIdx.x; t<WTOT; t+=256){
    int seg = 0;
    while(off[seg+1] <= t) seg++;
    int j = t - off[seg];
    Wc[t] = f ? ((const float*)ps[seg])[j] : b2f(((const bf16*)ps[seg])[j]);
  }
}

// ---------------- bucket-CSR build ----------------
__global__ void k_bhist(const int* __restrict__ dst, int* __restrict__ cnt){
  __shared__ int hist[NBUK];
  for(int j=threadIdx.x; j<NBUK; j+=256) hist[j] = 0;
  __syncthreads();
  int e0 = blockIdx.x*BATCH;
  int e1 = min(NE, e0+BATCH);
  for(int e=e0+threadIdx.x; e<e1; e+=256) atomicAdd(&hist[dst[e]>>6], 1);
  __syncthreads();
  for(int j=threadIdx.x; j<NBUK; j+=256) cnt[j*NBB + blockIdx.x] = hist[j];
}
// parallel 3-pass exclusive scan over cnt (CNTSZ elems, bucket-major)
__global__ void k_scanA(const int* __restrict__ cnt, int* __restrict__ tmp,
                        int* __restrict__ bsum){
  __shared__ int sh[1024];
  int gi = blockIdx.x*1024 + threadIdx.x;
  int v = (gi < CNTSZ) ? cnt[gi] : 0;
  sh[threadIdx.x] = v; __syncthreads();
  for(int off=1; off<1024; off<<=1){
    int t = (threadIdx.x>=off) ? sh[threadIdx.x-off] : 0;
    __syncthreads();
    sh[threadIdx.x] += t;
    __syncthreads();
  }
  if(gi < CNTSZ) tmp[gi] = sh[threadIdx.x];
  if(threadIdx.x == 1023) bsum[blockIdx.x] = sh[1023];
}
__global__ void k_scanB(const int* __restrict__ bsum, int* __restrict__ boff){
  __shared__ int sh[128];
  int v = (threadIdx.x < SCANB) ? bsum[threadIdx.x] : 0;
  sh[threadIdx.x] = v; __syncthreads();
  for(int off=1; off<128; off<<=1){
    int t = (threadIdx.x>=off) ? sh[threadIdx.x-off] : 0;
    __syncthreads();
    sh[threadIdx.x] += t;
    __syncthreads();
  }
  boff[threadIdx.x] = sh[threadIdx.x] - v;   // exclusive
}
__global__ void k_scanC(int* __restrict__ cnt, const int* __restrict__ tmp,
                        const int* __restrict__ boff, int* __restrict__ bucketStart){
  int gi = blockIdx.x*1024 + threadIdx.x;
  if(gi < CNTSZ){
    int orig = cnt[gi];
    int excl = tmp[gi] - orig + boff[gi>>10];
    cnt[gi] = excl;
    if(gi % NBB == 0) bucketStart[gi/NBB] = excl;
  }
  if(gi == 0) bucketStart[NBUK] = NE;
}
__global__ void k_bplace(const int* __restrict__ src, const int* __restrict__ dst,
                         const int* __restrict__ cnt, int* __restrict__ epk){
  __shared__ int cur[NBUK];
  for(int j=threadIdx.x; j<NBUK; j+=256) cur[j] = cnt[j*NBB + blockIdx.x];
  __syncthreads();
  int e0 = blockIdx.x*BATCH, e1 = min(NE, e0+BATCH);
  for(int e=e0+threadIdx.x; e<e1; e+=256){
    int d = dst[e];
    int pos = atomicAdd(&cur[d>>6], 1);
    epk[pos] = (src[e]<<6) | (d&63);
  }
}
// in-bucket counting sort -> exact node-grouped CSR (rowptr, srcS) + dinv.
__global__ void k_bsort(const int* __restrict__ bucketStart, const int* __restrict__ epk,
                        int* __restrict__ srcS, int* __restrict__ rowptr,
                        float* __restrict__ dinv){
  __shared__ int hist[64], excl[64], cur[64];
  int tid = threadIdx.x;
  if(tid < 64) hist[tid] = 0;
  __syncthreads();
  int b = blockIdx.x, beg = bucketStart[b], end = bucketStart[b+1];
  for(int p=beg+tid; p<end; p+=256) atomicAdd(&hist[epk[p]&63], 1);
  __syncthreads();
  if(tid == 0){
    int run = 0;
    for(int j=0;j<64;j++){ excl[j] = run; run += hist[j]; }
  }
  __syncthreads();
  if(tid < 64){
    int g = b*64 + tid;
    if(g < NN){
      rowptr[g] = beg + excl[tid];
      dinv[g]   = rsqrtf((float)(hist[tid] + 1));   // +1 self-loop
    }
    cur[tid] = excl[tid];
  }
  if(b == 0 && tid == 0) rowptr[NN] = NE;
  __syncthreads();
  for(int p=beg+tid; p<end; p+=256){
    int pk = epk[p];
    int pos = atomicAdd(&cur[pk&63], 1);
    srcS[beg+pos] = pk>>6;
  }
}

// ---------------- layer 1 (propagate-then-transform; X has 2 channels) ----------------
__global__ void k_xd(const void* __restrict__ xv, const int* __restrict__ flag,
                     const float* __restrict__ dinv, float2* __restrict__ xd){
  int i = blockIdx.x*256 + threadIdx.x;
  if(i >= NN) return;
  float x0, x1;
  if(*flag){ float2 p = ((const float2*)xv)[i]; x0=p.x; x1=p.y; }
  else     { const bf16* xp=(const bf16*)xv; x0=b2f(xp[2*i]); x1=b2f(xp[2*i+1]); }
  float d = dinv[i];
  xd[i] = make_float2(x0*d, x1*d);
}
__global__ void k_prop_x(const int* __restrict__ rowptr, const int* __restrict__ srcS,
                         const float2* __restrict__ xd, float2* __restrict__ y){
  int i = blockIdx.x*256 + threadIdx.x;
  if(i >= NN) return;
  int beg = rowptr[i], end = rowptr[i+1];
  float2 self = xd[i];
  float ax0 = self.x, ay0 = self.y;
  float ax1=0,ay1=0, ax2=0,ay2=0, ax3=0,ay3=0;
  int p = beg;
  for(; p+4 <= end; p += 4){
    int s0=srcS[p], s1=srcS[p+1], s2=srcS[p+2], s3=srcS[p+3];
    float2 v0=xd[s0], v1=xd[s1], v2=xd[s2], v3=xd[s3];
    ax0+=v0.x; ay0+=v0.y; ax1+=v1.x; ay1+=v1.y;
    ax2+=v2.x; ay2+=v2.y; ax3+=v3.x; ay3+=v3.y;
  }
  for(; p<end; p++){ float2 v=xd[srcS[p]]; ax0+=v.x; ay0+=v.y; }
  y[i] = make_float2((ax0+ax1)+(ax2+ax3), (ay0+ay1)+(ay2+ay3));
}
__global__ void k_transform1b(const float2* __restrict__ y, const float* __restrict__ Wc,
                              const float* __restrict__ dinv, bf16* __restrict__ h){
  __shared__ float W1s[128];
  __shared__ float bs[64];
  if(threadIdx.x < 128) W1s[threadIdx.x] = Wc[W1F + threadIdx.x];
  if(threadIdx.x < 64)  bs[threadIdx.x]  = Wc[B1F + threadIdx.x];
  __syncthreads();
  int t = blockIdx.x*256 + threadIdx.x;   // grid NN*8 threads
  int i = t>>3, g = t&7;
  float2 yv = y[i];
  float d = dinv[i];
  us8_t o;
  #pragma unroll
  for(int j=0;j<8;j++){
    int c = g*8+j;
    o[j] = f2us(fmaxf(d*(yv.x*W1s[c] + yv.y*W1s[64+c]) + bs[c], 0.0f));
  }
  *(us8_t*)((unsigned short*)h + (size_t)i*64 + g*8) = o;
}

// ---------------- 64->64 transform (LDS-tiled GEMM, 4x4 tile/thread) ----------------
__global__ void __launch_bounds__(256) k_transform64(
    const bf16* __restrict__ h, const float* __restrict__ W,
    const float* __restrict__ dinv, bf16* __restrict__ s){
  __shared__ float Ws[64*64];
  __shared__ float hs[64][68];
  __shared__ float dl[64];
  int tid = threadIdx.x;
  for(int j=tid; j<4096; j+=256) Ws[j] = W[j];
  int row0 = blockIdx.x*64;
  if(tid < 64){ int r = row0+tid; dl[tid] = (r<NN)? dinv[r] : 0.0f; }
  for(int ch = tid; ch < 512; ch += 256){
    int r = ch>>3, c8 = (ch&7)*8;
    int gr = row0 + r;
    float f[8];
    if(gr < NN){
      us8_t v = *(const us8_t*)((const unsigned short*)h + (size_t)gr*64 + c8);
      #pragma unroll
      for(int j=0;j<8;j++) f[j] = us2f(v[j]);
    } else {
      #pragma unroll
      for(int j=0;j<8;j++) f[j] = 0.0f;
    }
    *(float4*)&hs[r][c8]   = make_float4(f[0],f[1],f[2],f[3]);
    *(float4*)&hs[r][c8+4] = make_float4(f[4],f[5],f[6],f[7]);
  }
  __syncthreads();
  int ty = tid>>4, tx = tid&15;
  float acc[4][4] = {{0}};
  #pragma unroll 8
  for(int k=0;k<64;k++){
    float4 b4 = *(const float4*)&Ws[k*64 + tx*4];
    float a0 = hs[ty*4+0][k];
    float a1 = hs[ty*4+1][k];
    float a2 = hs[ty*4+2][k];
    float a3 = hs[ty*4+3][k];
    acc[0][0] = fmaf(a0,b4.x,acc[0][0]); acc[0][1] = fmaf(a0,b4.y,acc[0][1]);
    acc[0][2] = fmaf(a0,b4.z,acc[0][2]); acc[0][3] = fmaf(a0,b4.w,acc[0][3]);
    acc[1][0] = fmaf(a1,b4.x,acc[1][0]); acc[1][1] = fmaf(a1,b4.y,acc[1][1]);
    acc[1][2] = fmaf(a1,b4.z,acc[1][2]); acc[1][3] = fmaf(a1,b4.w,acc[1][3]);
    acc[2][0] = fmaf(a2,b4.x,acc[2][0]); acc[2][1] = fmaf(a2,b4.y,acc[2][1]);
    acc[2][2] = fmaf(a2,b4.z,acc[2][2]); acc[2][3] = fmaf(a2,b4.w,acc[2][3]);
    acc[3][0] = fmaf(a3,b4.x,acc[3][0]); acc[3][1] = fmaf(a3,b4.y,acc[3][1]);
    acc[3][2] = fmaf(a3,b4.z,acc[3][2]); acc[3][3] = fmaf(a3,b4.w,acc[3][3]);
  }
  #pragma unroll
  for(int rr=0; rr<4; rr++){
    int r = row0 + ty*4 + rr;
    if(r < NN){
      float dv = dl[ty*4+rr];
      unsigned lo = f2us(acc[rr][0]*dv) | ((unsigned)f2us(acc[rr][1]*dv) << 16);
      unsigned hi = f2us(acc[rr][2]*dv) | ((unsigned)f2us(acc[rr][3]*dv) << 16);
      uint2 o; o.x = lo; o.y = hi;
      *(uint2*)((unsigned short*)s + (size_t)r*64 + tx*4) = o;
    }
  }
}

// ---------------- CSR aggregate + finalize: wave per node, 8 edges per wave-load ----------------
// lane: slot = lane>>3 (8 edge slots), oct = lane&7 (8-channel octet). us8 = 16B.
__global__ void __launch_bounds__(256) k_aggregate(
    const int* __restrict__ rowptr, const int* __restrict__ srcS,
    const bf16* __restrict__ s, const float* __restrict__ dinv,
    const float* __restrict__ bias, bf16* __restrict__ h){
  int wave = threadIdx.x>>6, lane = threadIdx.x&63;
  int i = blockIdx.x*4 + wave;            // grid = NN/4 = 25000 blocks
  if(i >= NN) return;
  int beg = rowptr[i], end = rowptr[i+1];
  int slot = lane>>3, oct = lane&7;
  const unsigned short* sp = (const unsigned short*)s;
  float a0[8] = {0,0,0,0,0,0,0,0};
  float a1[8] = {0,0,0,0,0,0,0,0};
  int p = beg;
  for(; p+16 <= end; p += 16){            // 16 edges in flight (2 per lane)
    int e0 = srcS[p + slot];
    int e1 = srcS[p + 8 + slot];
    us8_t v0 = *(const us8_t*)(sp + (size_t)e0*64 + oct*8);
    us8_t v1 = *(const us8_t*)(sp + (size_t)e1*64 + oct*8);
    #pragma unroll
    for(int j=0;j<8;j++){ a0[j] += us2f(v0[j]); a1[j] += us2f(v1[j]); }
  }
  for(; p+8 <= end; p += 8){
    int e0 = srcS[p + slot];
    us8_t v0 = *(const us8_t*)(sp + (size_t)e0*64 + oct*8);
    #pragma unroll
    for(int j=0;j<8;j++) a0[j] += us2f(v0[j]);
  }
  int rem = end - p;                      // 0..7 tail, one edge per low slot
  if(slot < rem){
    int e0 = srcS[p + slot];
    us8_t v0 = *(const us8_t*)(sp + (size_t)e0*64 + oct*8);
    #pragma unroll
    for(int j=0;j<8;j++) a1[j] += us2f(v0[j]);
  }
  // reduce across the 8 edge slots (lane bits 3,4,5)
  float c[8];
  #pragma unroll
  for(int j=0;j<8;j++){
    float v = a0[j] + a1[j];
    v += __shfl_xor(v, 8, 64);
    v += __shfl_xor(v, 16, 64);
    v += __shfl_xor(v, 32, 64);
    c[j] = v;
  }
  // self-loop + finalize
  us8_t sv = *(const us8_t*)(sp + (size_t)i*64 + oct*8);
  float dv = dinv[i];
  us8_t o;
  #pragma unroll
  for(int j=0;j<8;j++){
    float v = c[j] + us2f(sv[j]);
    o[j] = f2us(fmaxf(fmaf(dv, v, bias[oct*8+j]), 0.0f));
  }
  if(slot == 0)                           // lanes 0..7 store 128B contiguous
    *(us8_t*)((unsigned short*)h + (size_t)i*64 + oct*8) = o;
}

// ---------------- fc1: [NN x 64] @ [64 x 128] + b, relu -> f (bf16) ----------------
__global__ void __launch_bounds__(256) k_fc1(const bf16* __restrict__ h,
                                             const float* __restrict__ Wc,
                                             bf16* __restrict__ f){
  __shared__ float W1s[64*128];
  __shared__ float hs[64][68];
  __shared__ float bs[128];
  int tid = threadIdx.x;
  for(int j=tid; j<8192; j+=256) W1s[j] = Wc[FW1F+j];
  if(tid < 128) bs[tid] = Wc[FB1F+tid];
  int row0 = blockIdx.x*64;
  for(int ch = tid; ch < 512; ch += 256){
    int r = ch>>3, c8 = (ch&7)*8, gr = row0 + r;
    float fv[8];
    if(gr < NN){
      us8_t v = *(const us8_t*)((const unsigned short*)h + (size_t)gr*64 + c8);
      #pragma unroll
      for(int j=0;j<8;j++) fv[j] = us2f(v[j]);
    } else {
      #pragma unroll
      for(int j=0;j<8;j++) fv[j] = 0.0f;
    }
    *(float4*)&hs[r][c8]   = make_float4(fv[0],fv[1],fv[2],fv[3]);
    *(float4*)&hs[r][c8+4] = make_float4(fv[4],fv[5],fv[6],fv[7]);
  }
  __syncthreads();
  int ty = tid>>4, tx = tid&15;
  float acc[4][8] = {{0}};
  #pragma unroll 4
  for(int k=0;k<64;k++){
    float4 b0 = *(const float4*)&W1s[k*128 + tx*8];
    float4 b1 = *(const float4*)&W1s[k*128 + tx*8 + 4];
    float a0 = hs[ty*4+0][k], a1 = hs[ty*4+1][k];
    float a2 = hs[ty*4+2][k], a3 = hs[ty*4+3][k];
    acc[0][0]=fmaf(a0,b0.x,acc[0][0]); acc[0][1]=fmaf(a0,b0.y,acc[0][1]);
    acc[0][2]=fmaf(a0,b0.z,acc[0][2]); acc[0][3]=fmaf(a0,b0.w,acc[0][3]);
    acc[0][4]=fmaf(a0,b1.x,acc[0][4]); acc[0][5]=fmaf(a0,b1.y,acc[0][5]);
    acc[0][6]=fmaf(a0,b1.z,acc[0][6]); acc[0][7]=fmaf(a0,b1.w,acc[0][7]);
    acc[1][0]=fmaf(a1,b0.x,acc[1][0]); acc[1][1]=fmaf(a1,b0.y,acc[1][1]);
    acc[1][2]=fmaf(a1,b0.z,acc[1][2]); acc[1][3]=fmaf(a1,b0.w,acc[1][3]);
    acc[1][4]=fmaf(a1,b1.x,acc[1][4]); acc[1][5]=fmaf(a1,b1.y,acc[1][5]);
    acc[1][6]=fmaf(a1,b1.z,acc[1][6]); acc[1][7]=fmaf(a1,b1.w,acc[1][7]);
    acc[2][0]=fmaf(a2,b0.x,acc[2][0]); acc[2][1]=fmaf(a2,b0.y,acc[2][1]);
    acc[2][2]=fmaf(a2,b0.z,acc[2][2]); acc[2][3]=fmaf(a2,b0.w,acc[2][3]);
    acc[2][4]=fmaf(a2,b1.x,acc[2][4]); acc[2][5]=fmaf(a2,b1.y,acc[2][5]);
    acc[2][6]=fmaf(a2,b1.z,acc[2][6]); acc[2][7]=fmaf(a2,b1.w,acc[2][7]);
    acc[3][0]=fmaf(a3,b0.x,acc[3][0]); acc[3][1]=fmaf(a3,b0.y,acc[3][1]);
    acc[3][2]=fmaf(a3,b0.z,acc[3][2]); acc[3][3]=fmaf(a3,b0.w,acc[3][3]);
    acc[3][4]=fmaf(a3,b1.x,acc[3][4]); acc[3][5]=fmaf(a3,b1.y,acc[3][5]);
    acc[3][6]=fmaf(a3,b1.z,acc[3][6]); acc[3][7]=fmaf(a3,b1.w,acc[3][7]);
  }
  #pragma unroll
  for(int r=0;r<4;r++){
    int gr = row0 + ty*4 + r;
    if(gr < NN){
      us8_t o;
      #pragma unroll
      for(int j=0;j<8;j++) o[j] = f2us(fmaxf(acc[r][j] + bs[tx*8+j], 0.0f));
      *(us8_t*)((unsigned short*)f + (size_t)gr*128 + tx*8) = o;
    }
  }
}

// ---------------- fc2: [NN x 128] @ [128 x 32] + b -> out ----------------
__global__ void __launch_bounds__(256) k_fc2(const bf16* __restrict__ f,
                                             const float* __restrict__ Wc,
                                             const int* __restrict__ flag,
                                             void* __restrict__ outv){
  __shared__ float W2s[128*32];
  __shared__ float fs[64][132];
  __shared__ float bs[32];
  int tid = threadIdx.x;
  for(int j=tid; j<4096; j+=256) W2s[j] = Wc[FW2F+j];
  if(tid < 32) bs[tid] = Wc[FB2F+tid];
  int row0 = blockIdx.x*64;
  for(int ch = tid; ch < 1024; ch += 256){
    int r = ch>>4, c8 = (ch&15)*8, gr = row0 + r;
    float fv[8];
    if(gr < NN){
      us8_t v = *(const us8_t*)((const unsigned short*)f + (size_t)gr*128 + c8);
      #pragma unroll
      for(int j=0;j<8;j++) fv[j] = us2f(v[j]);
    } else {
      #pragma unroll
      for(int j=0;j<8;j++) fv[j] = 0.0f;
    }
    *(float4*)&fs[r][c8]   = make_float4(fv[0],fv[1],fv[2],fv[3]);
    *(float4*)&fs[r][c8+4] = make_float4(fv[4],fv[5],fv[6],fv[7]);
  }
  __syncthreads();
  int ty = tid>>3, tx = tid&7;
  float acc[2][4] = {{0}};
  #pragma unroll 8
  for(int k=0;k<128;k++){
    float4 b4 = *(const float4*)&W2s[k*32 + tx*4];
    float a0 = fs[ty*2+0][k], a1 = fs[ty*2+1][k];
    acc[0][0]=fmaf(a0,b4.x,acc[0][0]); acc[0][1]=fmaf(a0,b4.y,acc[0][1]);
    acc[0][2]=fmaf(a0,b4.z,acc[0][2]); acc[0][3]=fmaf(a0,b4.w,acc[0][3]);
    acc[1][0]=fmaf(a1,b4.x,acc[1][0]); acc[1][1]=fmaf(a1,b4.y,acc[1][1]);
    acc[1][2]=fmaf(a1,b4.z,acc[1][2]); acc[1][3]=fmaf(a1,b4.w,acc[1][3]);
  }
  int fl = *flag;
  #pragma unroll
  for(int r=0;r<2;r++){
    int gr = row0 + ty*2 + r;
    if(gr < NN){
      float o0 = acc[r][0]+bs[tx*4+0], o1 = acc[r][1]+bs[tx*4+1];
      float o2 = acc[r][2]+bs[tx*4+2], o3 = acc[r][3]+bs[tx*4+3];
      if(fl){
        *(float4*)((float*)outv + (size_t)gr*32 + tx*4) = make_float4(o0,o1,o2,o3);
      } else {
        unsigned lo = f2us(o0) | ((unsigned)f2us(o1)<<16);
        unsigned hi = f2us(o2) | ((unsigned)f2us(o3)<<16);
        uint2 o; o.x = lo; o.y = hi;
        *(uint2*)((unsigned short*)outv + (size_t)gr*32 + tx*4) = o;
      }
    }
  }
}

extern "C" void kernel_launch(void* const* d_in, const int* in_sizes, int n_in,
                              void* d_out, int out_size, void* d_ws, size_t ws_size,
                              hipStream_t stream){
  const void* x   = d_in[0];
  const int*  ei  = (const int*)d_in[1];
  const int* srcI = ei;        // edge_index[0]
  const int* dstI = ei + NE;   // edge_index[1]

  // workspace layout (bytes); total ~67 MB
  char*   base   = (char*)d_ws;
  int*    flag   = (int*)   (base + 0);          // 256
  float*  Wc     = (float*) (base + 256);        // 83840 -> 84096
  int*    bstart = (int*)   (base + 84224);      // 6256
  int*    cnt    = (int*)   (base + 90624);      // 306348
  int*    tmpS   = (int*)   (base + 397056);     // 306348
  int*    bsum   = (int*)   (base + 703488);     // 512
  int*    boff   = (int*)   (base + 704000);     // 512
  float*  dinv   = (float*) (base + 704512);     // 400000
  int*    rowptr = (int*)   (base + 1104512);    // 400004
  int*    epk    = (int*)   (base + 1504640);    // 6400000
  int*    srcS   = (int*)   (base + 7904640);    // 6400000
  float2* xd     = (float2*)(base + 14304640);   // 800000
  float2* y      = (float2*)(base + 15104640);   // 800000
  bf16*   s      = (bf16*)  (base + 15904640);   // 12800000
  bf16*   h      = (bf16*)  (base + 28704640);   // 12800000
  bf16*   f      = (bf16*)  (base + 41504640);   // 25600000 -> ends 67104640

  k_sniff<<<1, 1024, 0, stream>>>((const unsigned short*)x, flag);
  k_convert_w<<<1, 256, 0, stream>>>(d_in[2], d_in[3], d_in[4], d_in[5], d_in[6],
                                     d_in[7], d_in[8], d_in[9], d_in[10], d_in[11],
                                     flag, Wc);

  // bucket-grouped build: hist -> parallel scan -> place -> in-bucket sort
  k_bhist <<<NBB, 256, 0, stream>>>(dstI, cnt);
  k_scanA <<<SCANB, 1024, 0, stream>>>(cnt, tmpS, bsum);
  k_scanB <<<1, 128, 0, stream>>>(bsum, boff);
  k_scanC <<<SCANB, 1024, 0, stream>>>(cnt, tmpS, boff, bstart);
  k_bplace<<<NBB, 256, 0, stream>>>(srcI, dstI, cnt, epk);
  k_bsort <<<NBUK, 256, 0, stream>>>(bstart, epk, srcS, rowptr, dinv);

  // layer 1 (2 -> 64): propagate x first (8B gathers), then transform
  k_xd         <<<(NN+255)/256, 256, 0, stream>>>(x, flag, dinv, xd);
  k_prop_x     <<<(NN+255)/256, 256, 0, stream>>>(rowptr, srcS, xd, y);
  k_transform1b<<<NN*8/256, 256, 0, stream>>>(y, Wc, dinv, h);

  // layer 2 (64 -> 64)
  k_transform64<<<(NN+63)/64, 256, 0, stream>>>(h, Wc+W2F, dinv, s);
  k_aggregate  <<<NN/4, 256, 0, stream>>>(rowptr, srcS, s, dinv, Wc+B2F, h);

  // layer 3 (64 -> 64)
  k_transform64<<<(NN+63)/64, 256, 0, stream>>>(h, Wc+W3F, dinv, s);
  k_aggregate  <<<NN/4, 256, 0, stream>>>(rowptr, srcS, s, dinv, Wc+B3F, h);

  // fc1 + fc2 (register-tiled GEMMs)
  k_fc1<<<(NN+63)/64, 256, 0, stream>>>(h, Wc, f);
  k_fc2<<<(NN+63)/64, 256, 0, stream>>>(f, Wc, flag, d_out);
}

// Round 10
// 415.078 us; speedup vs baseline: 4.1904x; 1.1852x over previous
//
#include <hip/hip_runtime.h>
#include <hip/hip_bf16.h>

#define NN 100000
#define NE 1600000
#define NBUK 1563          // ceil(NN/64) 64-node dst buckets
#define NBB  196           // histogram/place blocks (8192 edges each)
#define BATCH 8192
#define CNTSZ (NBUK*NBB)   // 306348
#define SCANB 300          // ceil(CNTSZ/1024)

using bf16 = __hip_bfloat16;
typedef unsigned short us8_t __attribute__((ext_vector_type(8)));
static __device__ __forceinline__ float b2f(bf16 v){ return __bfloat162float(v); }
static __device__ __forceinline__ bf16 f2b(float v){ return __float2bfloat16(v); }
static __device__ __forceinline__ float us2f(unsigned u){
  unsigned x = u<<16; float f; __builtin_memcpy(&f,&x,4); return f;
}
static __device__ __forceinline__ unsigned short f2us(float v){
  bf16 b = f2b(v); unsigned short u; __builtin_memcpy(&u,&b,2); return u;
}

// canonical f32 weight-pool offsets (floats)
#define W1F   0
#define B1F   128
#define W2F   192
#define B2F   4288
#define W3F   4352
#define B3F   8448
#define FW1F  8512
#define FB1F  16704
#define FW2F  16832
#define FB2F  20928
#define WTOT  20960

// ---- dtype sniff (f32 vs bf16 storage) ----
__global__ void k_sniff(const unsigned short* __restrict__ xr, int* flag){
  __shared__ int found;
  if(threadIdx.x==0) found = 0;
  __syncthreads();
  int loc = 0;
  for(int i=threadIdx.x*2; i<200000; i+=2048){
    unsigned e = (xr[i]>>7)&0xFF;
    if(e==0xFFu || e==0u) loc = 1;
  }
  if(loc) found = 1;
  __syncthreads();
  if(threadIdx.x==0) *flag = found;   // 1 = f32 storage, 0 = bf16 storage
}

__global__ void k_convert_w(const void* p0,const void* p1,const void* p2,const void* p3,
                            const void* p4,const void* p5,const void* p6,const void* p7,
                            const void* p8,const void* p9,
                            const int* __restrict__ flag, float* __restrict__ Wc){
  const void* ps[10] = {p0,p1,p2,p3,p4,p5,p6,p7,p8,p9};
  const int off[11] = {W1F,B1F,W2F,B2F,W3F,B3F,FW1F,FB1F,FW2F,FB2F,WTOT};
  int f = *flag;
  for(int t=threadIdx.x; t<WTOT; t+=256){
    int seg = 0;
    while(off[seg+1] <= t) seg++;
    int j = t - off[seg];
    Wc[t] = f ? ((const float*)ps[seg])[j] : b2f(((const bf16*)ps[seg])[j]);
  }
}

// ---------------- bucket-CSR build ----------------
__global__ void k_bhist(const int* __restrict__ dst, int* __restrict__ cnt){
  __shared__ int hist[NBUK];
  for(int j=threadIdx.x; j<NBUK; j+=512) hist[j] = 0;
  __syncthreads();
  int e0 = blockIdx.x*BATCH;
  int e1 = min(NE, e0+BATCH);
  for(int e=e0+threadIdx.x; e<e1; e+=512) atomicAdd(&hist[dst[e]>>6], 1);
  __syncthreads();
  for(int j=threadIdx.x; j<NBUK; j+=512) cnt[j*NBB + blockIdx.x] = hist[j];
}
// parallel 3-pass exclusive scan over cnt (CNTSZ elems, bucket-major)
__global__ void k_scanA(const int* __restrict__ cnt, int* __restrict__ tmp,
                        int* __restrict__ bsum){
  __shared__ int sh[1024];
  int gi = blockIdx.x*1024 + threadIdx.x;
  int v = (gi < CNTSZ) ? cnt[gi] : 0;
  sh[threadIdx.x] = v; __syncthreads();
  for(int off=1; off<1024; off<<=1){
    int t = (threadIdx.x>=off) ? sh[threadIdx.x-off] : 0;
    __syncthreads();
    sh[threadIdx.x] += t;
    __syncthreads();
  }
  if(gi < CNTSZ) tmp[gi] = sh[threadIdx.x];
  if(threadIdx.x == 1023) bsum[blockIdx.x] = sh[1023];
}
__global__ void k_scanB(const int* __restrict__ bsum, int* __restrict__ boff){
  __shared__ int sh[512];
  int v = (threadIdx.x < SCANB) ? bsum[threadIdx.x] : 0;
  sh[threadIdx.x] = v; __syncthreads();
  for(int off=1; off<512; off<<=1){
    int t = (threadIdx.x>=off) ? sh[threadIdx.x-off] : 0;
    __syncthreads();
    sh[threadIdx.x] += t;
    __syncthreads();
  }
  boff[threadIdx.x] = sh[threadIdx.x] - v;   // exclusive
}
__global__ void k_scanC(int* __restrict__ cnt, const int* __restrict__ tmp,
                        const int* __restrict__ boff, int* __restrict__ bucketStart){
  int gi = blockIdx.x*1024 + threadIdx.x;
  if(gi < CNTSZ){
    int orig = cnt[gi];
    int excl = tmp[gi] - orig + boff[gi>>10];
    cnt[gi] = excl;
    if(gi % NBB == 0) bucketStart[gi/NBB] = excl;
  }
  if(gi == 0) bucketStart[NBUK] = NE;
}
__global__ void k_bplace(const int* __restrict__ src, const int* __restrict__ dst,
                         const int* __restrict__ cnt, int* __restrict__ epk){
  __shared__ int cur[NBUK];
  for(int j=threadIdx.x; j<NBUK; j+=512) cur[j] = cnt[j*NBB + blockIdx.x];
  __syncthreads();
  int e0 = blockIdx.x*BATCH, e1 = min(NE, e0+BATCH);
  for(int e=e0+threadIdx.x; e<e1; e+=512){
    int d = dst[e];
    int pos = atomicAdd(&cur[d>>6], 1);
    epk[pos] = (src[e]<<6) | (d&63);
  }
}
// in-bucket counting sort -> exact node-grouped CSR (rowptr, srcS) + dinv.
__global__ void k_bsort(const int* __restrict__ bucketStart, const int* __restrict__ epk,
                        int* __restrict__ srcS, int* __restrict__ rowptr,
                        float* __restrict__ dinv){
  __shared__ int hist[64], excl[64], cur[64];
  int tid = threadIdx.x;
  if(tid < 64) hist[tid] = 0;
  __syncthreads();
  int b = blockIdx.x, beg = bucketStart[b], end = bucketStart[b+1];
  for(int p=beg+tid; p<end; p+=256) atomicAdd(&hist[epk[p]&63], 1);
  __syncthreads();
  if(tid == 0){
    int run = 0;
    for(int j=0;j<64;j++){ excl[j] = run; run += hist[j]; }
  }
  __syncthreads();
  if(tid < 64){
    int g = b*64 + tid;
    if(g < NN){
      rowptr[g] = beg + excl[tid];
      dinv[g]   = rsqrtf((float)(hist[tid] + 1));   // +1 self-loop
    }
    cur[tid] = excl[tid];
  }
  if(b == 0 && tid == 0) rowptr[NN] = NE;
  __syncthreads();
  for(int p=beg+tid; p<end; p+=256){
    int pk = epk[p];
    int pos = atomicAdd(&cur[pk&63], 1);
    srcS[beg+pos] = pk>>6;
  }
}

// ---------------- layer 1 (propagate-then-transform; X has 2 channels) ----------------
__global__ void k_xd(const void* __restrict__ xv, const int* __restrict__ flag,
                     const float* __restrict__ dinv, float2* __restrict__ xd){
  int i = blockIdx.x*256 + threadIdx.x;
  if(i >= NN) return;
  float x0, x1;
  if(*flag){ float2 p = ((const float2*)xv)[i]; x0=p.x; x1=p.y; }
  else     { const bf16* xp=(const bf16*)xv; x0=b2f(xp[2*i]); x1=b2f(xp[2*i+1]); }
  float d = dinv[i];
  xd[i] = make_float2(x0*d, x1*d);
}
__global__ void k_prop_x(const int* __restrict__ rowptr, const int* __restrict__ srcS,
                         const float2* __restrict__ xd, float2* __restrict__ y){
  int i = blockIdx.x*256 + threadIdx.x;
  if(i >= NN) return;
  int beg = rowptr[i], end = rowptr[i+1];
  float2 self = xd[i];
  float ax0 = self.x, ay0 = self.y;
  float ax1=0,ay1=0, ax2=0,ay2=0, ax3=0,ay3=0;
  int p = beg;
  for(; p+4 <= end; p += 4){
    int s0=srcS[p], s1=srcS[p+1], s2=srcS[p+2], s3=srcS[p+3];
    float2 v0=xd[s0], v1=xd[s1], v2=xd[s2], v3=xd[s3];
    ax0+=v0.x; ay0+=v0.y; ax1+=v1.x; ay1+=v1.y;
    ax2+=v2.x; ay2+=v2.y; ax3+=v3.x; ay3+=v3.y;
  }
  for(; p<end; p++){ float2 v=xd[srcS[p]]; ax0+=v.x; ay0+=v.y; }
  y[i] = make_float2((ax0+ax1)+(ax2+ax3), (ay0+ay1)+(ay2+ay3));
}
__global__ void k_transform1b(const float2* __restrict__ y, const float* __restrict__ Wc,
                              const float* __restrict__ dinv, bf16* __restrict__ h){
  __shared__ float W1s[128];
  __shared__ float bs[64];
  if(threadIdx.x < 128) W1s[threadIdx.x] = Wc[W1F + threadIdx.x];
  if(threadIdx.x < 64)  bs[threadIdx.x]  = Wc[B1F + threadIdx.x];
  __syncthreads();
  int t = blockIdx.x*256 + threadIdx.x;   // grid NN*8 threads
  int i = t>>3, g = t&7;
  float2 yv = y[i];
  float d = dinv[i];
  us8_t o;
  #pragma unroll
  for(int j=0;j<8;j++){
    int c = g*8+j;
    o[j] = f2us(fmaxf(d*(yv.x*W1s[c] + yv.y*W1s[64+c]) + bs[c], 0.0f));
  }
  *(us8_t*)((unsigned short*)h + (size_t)i*64 + g*8) = o;
}

// ---------------- 64->64 transform (LDS-tiled GEMM, 4x4 tile/thread) ----------------
__global__ void __launch_bounds__(256) k_transform64(
    const bf16* __restrict__ h, const float* __restrict__ W,
    const float* __restrict__ dinv, bf16* __restrict__ s){
  __shared__ float Ws[64*64];
  __shared__ float hs[64][68];
  __shared__ float dl[64];
  int tid = threadIdx.x;
  for(int j=tid; j<4096; j+=256) Ws[j] = W[j];
  int row0 = blockIdx.x*64;
  if(tid < 64){ int r = row0+tid; dl[tid] = (r<NN)? dinv[r] : 0.0f; }
  for(int ch = tid; ch < 512; ch += 256){
    int r = ch>>3, c8 = (ch&7)*8;
    int gr = row0 + r;
    float f[8];
    if(gr < NN){
      us8_t v = *(const us8_t*)((const unsigned short*)h + (size_t)gr*64 + c8);
      #pragma unroll
      for(int j=0;j<8;j++) f[j] = us2f(v[j]);
    } else {
      #pragma unroll
      for(int j=0;j<8;j++) f[j] = 0.0f;
    }
    *(float4*)&hs[r][c8]   = make_float4(f[0],f[1],f[2],f[3]);
    *(float4*)&hs[r][c8+4] = make_float4(f[4],f[5],f[6],f[7]);
  }
  __syncthreads();
  int ty = tid>>4, tx = tid&15;
  float acc[4][4] = {{0}};
  #pragma unroll 8
  for(int k=0;k<64;k++){
    float4 b4 = *(const float4*)&Ws[k*64 + tx*4];
    float a0 = hs[ty*4+0][k];
    float a1 = hs[ty*4+1][k];
    float a2 = hs[ty*4+2][k];
    float a3 = hs[ty*4+3][k];
    acc[0][0] = fmaf(a0,b4.x,acc[0][0]); acc[0][1] = fmaf(a0,b4.y,acc[0][1]);
    acc[0][2] = fmaf(a0,b4.z,acc[0][2]); acc[0][3] = fmaf(a0,b4.w,acc[0][3]);
    acc[1][0] = fmaf(a1,b4.x,acc[1][0]); acc[1][1] = fmaf(a1,b4.y,acc[1][1]);
    acc[1][2] = fmaf(a1,b4.z,acc[1][2]); acc[1][3] = fmaf(a1,b4.w,acc[1][3]);
    acc[2][0] = fmaf(a2,b4.x,acc[2][0]); acc[2][1] = fmaf(a2,b4.y,acc[2][1]);
    acc[2][2] = fmaf(a2,b4.z,acc[2][2]); acc[2][3] = fmaf(a2,b4.w,acc[2][3]);
    acc[3][0] = fmaf(a3,b4.x,acc[3][0]); acc[3][1] = fmaf(a3,b4.y,acc[3][1]);
    acc[3][2] = fmaf(a3,b4.z,acc[3][2]); acc[3][3] = fmaf(a3,b4.w,acc[3][3]);
  }
  #pragma unroll
  for(int rr=0; rr<4; rr++){
    int r = row0 + ty*4 + rr;
    if(r < NN){
      float dv = dl[ty*4+rr];
      unsigned lo = f2us(acc[rr][0]*dv) | ((unsigned)f2us(acc[rr][1]*dv) << 16);
      unsigned hi = f2us(acc[rr][2]*dv) | ((unsigned)f2us(acc[rr][3]*dv) << 16);
      uint2 o; o.x = lo; o.y = hi;
      *(uint2*)((unsigned short*)s + (size_t)r*64 + tx*4) = o;
    }
  }
}

// ---------------- CSR aggregate + finalize: wave per node, 8 edges per wave-load ----------------
__global__ void __launch_bounds__(256) k_aggregate(
    const int* __restrict__ rowptr, const int* __restrict__ srcS,
    const bf16* __restrict__ s, const float* __restrict__ dinv,
    const float* __restrict__ bias, bf16* __restrict__ h){
  int wave = threadIdx.x>>6, lane = threadIdx.x&63;
  int i = blockIdx.x*4 + wave;            // grid = NN/4 = 25000 blocks
  if(i >= NN) return;
  int beg = rowptr[i], end = rowptr[i+1];
  int slot = lane>>3, oct = lane&7;
  const unsigned short* sp = (const unsigned short*)s;
  float a0[8] = {0,0,0,0,0,0,0,0};
  float a1[8] = {0,0,0,0,0,0,0,0};
  int p = beg;
  for(; p+16 <= end; p += 16){            // 16 edges in flight (2 per lane)
    int e0 = srcS[p + slot];
    int e1 = srcS[p + 8 + slot];
    us8_t v0 = *(const us8_t*)(sp + (size_t)e0*64 + oct*8);
    us8_t v1 = *(const us8_t*)(sp + (size_t)e1*64 + oct*8);
    #pragma unroll
    for(int j=0;j<8;j++){ a0[j] += us2f(v0[j]); a1[j] += us2f(v1[j]); }
  }
  for(; p+8 <= end; p += 8){
    int e0 = srcS[p + slot];
    us8_t v0 = *(const us8_t*)(sp + (size_t)e0*64 + oct*8);
    #pragma unroll
    for(int j=0;j<8;j++) a0[j] += us2f(v0[j]);
  }
  int rem = end - p;                      // 0..7 tail, one edge per low slot
  if(slot < rem){
    int e0 = srcS[p + slot];
    us8_t v0 = *(const us8_t*)(sp + (size_t)e0*64 + oct*8);
    #pragma unroll
    for(int j=0;j<8;j++) a1[j] += us2f(v0[j]);
  }
  // reduce across the 8 edge slots (lane bits 3,4,5)
  float c[8];
  #pragma unroll
  for(int j=0;j<8;j++){
    float v = a0[j] + a1[j];
    v += __shfl_xor(v, 8, 64);
    v += __shfl_xor(v, 16, 64);
    v += __shfl_xor(v, 32, 64);
    c[j] = v;
  }
  // self-loop + finalize
  us8_t sv = *(const us8_t*)(sp + (size_t)i*64 + oct*8);
  float dv = dinv[i];
  us8_t o;
  #pragma unroll
  for(int j=0;j<8;j++){
    float v = c[j] + us2f(sv[j]);
    o[j] = f2us(fmaxf(fmaf(dv, v, bias[oct*8+j]), 0.0f));
  }
  if(slot == 0)                           // lanes 0..7 store 128B contiguous
    *(us8_t*)((unsigned short*)h + (size_t)i*64 + oct*8) = o;
}

// ---------------- fc1: [NN x 64] @ [64 x 128] + b, relu -> f (bf16) ----------------
__global__ void __launch_bounds__(256) k_fc1(const bf16* __restrict__ h,
                                             const float* __restrict__ Wc,
                                             bf16* __restrict__ f){
  __shared__ float W1s[64*128];
  __shared__ float hs[64][68];
  __shared__ float bs[128];
  int tid = threadIdx.x;
  for(int j=tid; j<8192; j+=256) W1s[j] = Wc[FW1F+j];
  if(tid < 128) bs[tid] = Wc[FB1F+tid];
  int row0 = blockIdx.x*64;
  for(int ch = tid; ch < 512; ch += 256){
    int r = ch>>3, c8 = (ch&7)*8, gr = row0 + r;
    float fv[8];
    if(gr < NN){
      us8_t v = *(const us8_t*)((const unsigned short*)h + (size_t)gr*64 + c8);
      #pragma unroll
      for(int j=0;j<8;j++) fv[j] = us2f(v[j]);
    } else {
      #pragma unroll
      for(int j=0;j<8;j++) fv[j] = 0.0f;
    }
    *(float4*)&hs[r][c8]   = make_float4(fv[0],fv[1],fv[2],fv[3]);
    *(float4*)&hs[r][c8+4] = make_float4(fv[4],fv[5],fv[6],fv[7]);
  }
  __syncthreads();
  int ty = tid>>4, tx = tid&15;
  float acc[4][8] = {{0}};
  #pragma unroll 4
  for(int k=0;k<64;k++){
    float4 b0 = *(const float4*)&W1s[k*128 + tx*8];
    float4 b1 = *(const float4*)&W1s[k*128 + tx*8 + 4];
    float a0 = hs[ty*4+0][k], a1 = hs[ty*4+1][k];
    float a2 = hs[ty*4+2][k], a3 = hs[ty*4+3][k];
    acc[0][0]=fmaf(a0,b0.x,acc[0][0]); acc[0][1]=fmaf(a0,b0.y,acc[0][1]);
    acc[0][2]=fmaf(a0,b0.z,acc[0][2]); acc[0][3]=fmaf(a0,b0.w,acc[0][3]);
    acc[0][4]=fmaf(a0,b1.x,acc[0][4]); acc[0][5]=fmaf(a0,b1.y,acc[0][5]);
    acc[0][6]=fmaf(a0,b1.z,acc[0][6]); acc[0][7]=fmaf(a0,b1.w,acc[0][7]);
    acc[1][0]=fmaf(a1,b0.x,acc[1][0]); acc[1][1]=fmaf(a1,b0.y,acc[1][1]);
    acc[1][2]=fmaf(a1,b0.z,acc[1][2]); acc[1][3]=fmaf(a1,b0.w,acc[1][3]);
    acc[1][4]=fmaf(a1,b1.x,acc[1][4]); acc[1][5]=fmaf(a1,b1.y,acc[1][5]);
    acc[1][6]=fmaf(a1,b1.z,acc[1][6]); acc[1][7]=fmaf(a1,b1.w,acc[1][7]);
    acc[2][0]=fmaf(a2,b0.x,acc[2][0]); acc[2][1]=fmaf(a2,b0.y,acc[2][1]);
    acc[2][2]=fmaf(a2,b0.z,acc[2][2]); acc[2][3]=fmaf(a2,b0.w,acc[2][3]);
    acc[2][4]=fmaf(a2,b1.x,acc[2][4]); acc[2][5]=fmaf(a2,b1.y,acc[2][5]);
    acc[2][6]=fmaf(a2,b1.z,acc[2][6]); acc[2][7]=fmaf(a2,b1.w,acc[2][7]);
    acc[3][0]=fmaf(a3,b0.x,acc[3][0]); acc[3][1]=fmaf(a3,b0.y,acc[3][1]);
    acc[3][2]=fmaf(a3,b0.z,acc[3][2]); acc[3][3]=fmaf(a3,b0.w,acc[3][3]);
    acc[3][4]=fmaf(a3,b1.x,acc[3][4]); acc[3][5]=fmaf(a3,b1.y,acc[3][5]);
    acc[3][6]=fmaf(a3,b1.z,acc[3][6]); acc[3][7]=fmaf(a3,b1.w,acc[3][7]);
  }
  #pragma unroll
  for(int r=0;r<4;r++){
    int gr = row0 + ty*4 + r;
    if(gr < NN){
      us8_t o;
      #pragma unroll
      for(int j=0;j<8;j++) o[j] = f2us(fmaxf(acc[r][j] + bs[tx*8+j], 0.0f));
      *(us8_t*)((unsigned short*)f + (size_t)gr*128 + tx*8) = o;
    }
  }
}

// ---------------- fc2: [NN x 128] @ [128 x 32] + b -> out ----------------
__global__ void __launch_bounds__(256) k_fc2(const bf16* __restrict__ f,
                                             const float* __restrict__ Wc,
                                             const int* __restrict__ flag,
                                             void* __restrict__ outv){
  __shared__ float W2s[128*32];
  __shared__ float fs[64][132];
  __shared__ float bs[32];
  int tid = threadIdx.x;
  for(int j=tid; j<4096; j+=256) W2s[j] = Wc[FW2F+j];
  if(tid < 32) bs[tid] = Wc[FB2F+tid];
  int row0 = blockIdx.x*64;
  for(int ch = tid; ch < 1024; ch += 256){
    int r = ch>>4, c8 = (ch&15)*8, gr = row0 + r;
    float fv[8];
    if(gr < NN){
      us8_t v = *(const us8_t*)((const unsigned short*)f + (size_t)gr*128 + c8);
      #pragma unroll
      for(int j=0;j<8;j++) fv[j] = us2f(v[j]);
    } else {
      #pragma unroll
      for(int j=0;j<8;j++) fv[j] = 0.0f;
    }
    *(float4*)&fs[r][c8]   = make_float4(fv[0],fv[1],fv[2],fv[3]);
    *(float4*)&fs[r][c8+4] = make_float4(fv[4],fv[5],fv[6],fv[7]);
  }
  __syncthreads();
  int ty = tid>>3, tx = tid&7;
  float acc[2][4] = {{0}};
  #pragma unroll 8
  for(int k=0;k<128;k++){
    float4 b4 = *(const float4*)&W2s[k*32 + tx*4];
    float a0 = fs[ty*2+0][k], a1 = fs[ty*2+1][k];
    acc[0][0]=fmaf(a0,b4.x,acc[0][0]); acc[0][1]=fmaf(a0,b4.y,acc[0][1]);
    acc[0][2]=fmaf(a0,b4.z,acc[0][2]); acc[0][3]=fmaf(a0,b4.w,acc[0][3]);
    acc[1][0]=fmaf(a1,b4.x,acc[1][0]); acc[1][1]=fmaf(a1,b4.y,acc[1][1]);
    acc[1][2]=fmaf(a1,b4.z,acc[1][2]); acc[1][3]=fmaf(a1,b4.w,acc[1][3]);
  }
  int fl = *flag;
  #pragma unroll
  for(int r=0;r<2;r++){
    int gr = row0 + ty*2 + r;
    if(gr < NN){
      float o0 = acc[r][0]+bs[tx*4+0], o1 = acc[r][1]+bs[tx*4+1];
      float o2 = acc[r][2]+bs[tx*4+2], o3 = acc[r][3]+bs[tx*4+3];
      if(fl){
        *(float4*)((float*)outv + (size_t)gr*32 + tx*4) = make_float4(o0,o1,o2,o3);
      } else {
        unsigned lo = f2us(o0) | ((unsigned)f2us(o1)<<16);
        unsigned hi = f2us(o2) | ((unsigned)f2us(o3)<<16);
        uint2 o; o.x = lo; o.y = hi;
        *(uint2*)((unsigned short*)outv + (size_t)gr*32 + tx*4) = o;
      }
    }
  }
}

extern "C" void kernel_launch(void* const* d_in, const int* in_sizes, int n_in,
                              void* d_out, int out_size, void* d_ws, size_t ws_size,
                              hipStream_t stream){
  const void* x   = d_in[0];
  const int*  ei  = (const int*)d_in[1];
  const int* srcI = ei;        // edge_index[0]
  const int* dstI = ei + NE;   // edge_index[1]

  // workspace layout (bytes); total ~69 MB
  char*   base   = (char*)d_ws;
  int*    flag   = (int*)   (base + 0);          // 256
  float*  Wc     = (float*) (base + 256);        // 83840 -> 84096
  int*    bstart = (int*)   (base + 84224);      // 6256
  int*    cnt    = (int*)   (base + 90624);      // 1225392
  int*    tmpS   = (int*)   (base + 1316096);    // 1225392
  int*    bsum   = (int*)   (base + 2541568);    // 2048
  int*    boff   = (int*)   (base + 2543616);    // 2048
  float*  dinv   = (float*) (base + 2545664);    // 400000
  int*    rowptr = (int*)   (base + 2945664);    // 400004
  int*    epk    = (int*)   (base + 3345792);    // 6400000
  int*    srcS   = (int*)   (base + 9745792);    // 6400000
  float2* xd     = (float2*)(base + 16145792);   // 800000
  float2* y      = (float2*)(base + 16945792);   // 800000
  bf16*   s      = (bf16*)  (base + 17745792);   // 12800000
  bf16*   h      = (bf16*)  (base + 30545792);   // 12800000
  bf16*   f      = (bf16*)  (base + 43345792);   // 25600000 -> ends 68945792

  k_sniff<<<1, 1024, 0, stream>>>((const unsigned short*)x, flag);
  k_convert_w<<<1, 256, 0, stream>>>(d_in[2], d_in[3], d_in[4], d_in[5], d_in[6],
                                     d_in[7], d_in[8], d_in[9], d_in[10], d_in[11],
                                     flag, Wc);

  // bucket-grouped build: hist -> parallel scan -> place -> in-bucket sort
  k_bhist <<<NBB, 512, 0, stream>>>(dstI, cnt);
  k_scanA <<<SCANB, 1024, 0, stream>>>(cnt, tmpS, bsum);
  k_scanB <<<1, 512, 0, stream>>>(bsum, boff);
  k_scanC <<<SCANB, 1024, 0, stream>>>(cnt, tmpS, boff, bstart);
  k_bplace<<<NBB, 512, 0, stream>>>(srcI, dstI, cnt, epk);
  k_bsort <<<NBUK, 256, 0, stream>>>(bstart, epk, srcS, rowptr, dinv);

  // layer 1 (2 -> 64): propagate x first (8B gathers), then transform
  k_xd         <<<(NN+255)/256, 256, 0, stream>>>(x, flag, dinv, xd);
  k_prop_x     <<<(NN+255)/256, 256, 0, stream>>>(rowptr, srcS, xd, y);
  k_transform1b<<<NN*8/256, 256, 0, stream>>>(y, Wc, dinv, h);

  // layer 2 (64 -> 64)
  k_transform64<<<(NN+63)/64, 256, 0, stream>>>(h, Wc+W2F, dinv, s);
  k_aggregate  <<<NN/4, 256, 0, stream>>>(rowptr, srcS, s, dinv, Wc+B2F, h);

  // layer 3 (64 -> 64)
  k_transform64<<<(NN+63)/64, 256, 0, stream>>>(h, Wc+W3F, dinv, s);
  k_aggregate  <<<NN/4, 256, 0, stream>>>(rowptr, srcS, s, dinv, Wc+B3F, h);

  // fc1 + fc2 (register-tiled GEMMs)
  k_fc1<<<(NN+63)/64, 256, 0, stream>>>(h, Wc, f);
  k_fc2<<<(NN+63)/64, 256, 0, stream>>>(f, Wc, flag, d_out);
}

// Round 11
// 329.255 us; speedup vs baseline: 5.2826x; 1.2607x over previous
//
#include <hip/hip_runtime.h>
#include <hip/hip_bf16.h>

#define NN 100000
#define NE 1600000
#define NBUK 1563          // ceil(NN/64) 64-node dst buckets
#define NBB  196           // histogram/place blocks (8192 edges each)
#define BATCH 8192
#define CNTSZ (NBUK*NBB)   // 306348
#define SCANB 300          // ceil(CNTSZ/1024)

using bf16 = __hip_bfloat16;
typedef unsigned short us8_t __attribute__((ext_vector_type(8)));
static __device__ __forceinline__ float b2f(bf16 v){ return __bfloat162float(v); }
static __device__ __forceinline__ bf16 f2b(float v){ return __float2bfloat16(v); }
static __device__ __forceinline__ float us2f(unsigned u){
  unsigned x = u<<16; float f; __builtin_memcpy(&f,&x,4); return f;
}
static __device__ __forceinline__ unsigned short f2us(float v){
  bf16 b = f2b(v); unsigned short u; __builtin_memcpy(&u,&b,2); return u;
}

// canonical f32 weight-pool offsets (floats)
#define W1F   0
#define B1F   128
#define W2F   192
#define B2F   4288
#define W3F   4352
#define B3F   8448
#define FW1F  8512
#define FB1F  16704
#define FW2F  16832
#define FB2F  20928
#define WTOT  20960

// ---- dtype sniff (f32 vs bf16 storage), multi-block ----
__global__ void k_flag0(int* flag){ if(threadIdx.x==0) *flag = 0; }
// even ushort slots of f32 storage are low-mantissa bits -> exponent field
// 0xFF/0x00 with P~0.8%; true bf16 N(0,1) never. Exhaustive scan of all
// 100000 even slots, coalesced, one atomicOr per block.
__global__ void k_sniffB(const unsigned short* __restrict__ xr, int* flag){
  __shared__ int found;
  if(threadIdx.x==0) found = 0;
  __syncthreads();
  int loc = 0;
  for(int si = blockIdx.x*256 + threadIdx.x; si < 100000; si += 98*256){
    unsigned e = (xr[si*2]>>7)&0xFF;
    if(e==0xFFu || e==0u) loc = 1;
  }
  if(loc) found = 1;
  __syncthreads();
  if(threadIdx.x==0 && found) atomicOr(flag, 1);   // 1 = f32 storage
}

// convert all weights/biases into canonical f32 pool — one element/thread
__global__ void k_convert_w(const void* p0,const void* p1,const void* p2,const void* p3,
                            const void* p4,const void* p5,const void* p6,const void* p7,
                            const void* p8,const void* p9,
                            const int* __restrict__ flag, float* __restrict__ Wc){
  int t = blockIdx.x*256 + threadIdx.x;
  if(t >= WTOT) return;
  const void* ps[10] = {p0,p1,p2,p3,p4,p5,p6,p7,p8,p9};
  const int off[11] = {W1F,B1F,W2F,B2F,W3F,B3F,FW1F,FB1F,FW2F,FB2F,WTOT};
  int seg = 0;
  while(off[seg+1] <= t) seg++;
  int j = t - off[seg];
  Wc[t] = (*flag) ? ((const float*)ps[seg])[j] : b2f(((const bf16*)ps[seg])[j]);
}

// ---------------- bucket-CSR build ----------------
__global__ void k_bhist(const int* __restrict__ dst, int* __restrict__ cnt){
  __shared__ int hist[NBUK];
  for(int j=threadIdx.x; j<NBUK; j+=512) hist[j] = 0;
  __syncthreads();
  int e0 = blockIdx.x*BATCH;
  int e1 = min(NE, e0+BATCH);
  for(int e=e0+threadIdx.x; e<e1; e+=512) atomicAdd(&hist[dst[e]>>6], 1);
  __syncthreads();
  for(int j=threadIdx.x; j<NBUK; j+=512) cnt[j*NBB + blockIdx.x] = hist[j];
}
// parallel 3-pass exclusive scan over cnt (CNTSZ elems, bucket-major)
__global__ void k_scanA(const int* __restrict__ cnt, int* __restrict__ tmp,
                        int* __restrict__ bsum){
  __shared__ int sh[1024];
  int gi = blockIdx.x*1024 + threadIdx.x;
  int v = (gi < CNTSZ) ? cnt[gi] : 0;
  sh[threadIdx.x] = v; __syncthreads();
  for(int off=1; off<1024; off<<=1){
    int t = (threadIdx.x>=off) ? sh[threadIdx.x-off] : 0;
    __syncthreads();
    sh[threadIdx.x] += t;
    __syncthreads();
  }
  if(gi < CNTSZ) tmp[gi] = sh[threadIdx.x];
  if(threadIdx.x == 1023) bsum[blockIdx.x] = sh[1023];
}
__global__ void k_scanB(const int* __restrict__ bsum, int* __restrict__ boff){
  __shared__ int sh[512];
  int v = (threadIdx.x < SCANB) ? bsum[threadIdx.x] : 0;
  sh[threadIdx.x] = v; __syncthreads();
  for(int off=1; off<512; off<<=1){
    int t = (threadIdx.x>=off) ? sh[threadIdx.x-off] : 0;
    __syncthreads();
    sh[threadIdx.x] += t;
    __syncthreads();
  }
  boff[threadIdx.x] = sh[threadIdx.x] - v;   // exclusive
}
__global__ void k_scanC(int* __restrict__ cnt, const int* __restrict__ tmp,
                        const int* __restrict__ boff, int* __restrict__ bucketStart){
  int gi = blockIdx.x*1024 + threadIdx.x;
  if(gi < CNTSZ){
    int orig = cnt[gi];
    int excl = tmp[gi] - orig + boff[gi>>10];
    cnt[gi] = excl;
    if(gi % NBB == 0) bucketStart[gi/NBB] = excl;
  }
  if(gi == 0) bucketStart[NBUK] = NE;
}
__global__ void k_bplace(const int* __restrict__ src, const int* __restrict__ dst,
                         const int* __restrict__ cnt, int* __restrict__ epk){
  __shared__ int cur[NBUK];
  for(int j=threadIdx.x; j<NBUK; j+=512) cur[j] = cnt[j*NBB + blockIdx.x];
  __syncthreads();
  int e0 = blockIdx.x*BATCH, e1 = min(NE, e0+BATCH);
  for(int e=e0+threadIdx.x; e<e1; e+=512){
    int d = dst[e];
    int pos = atomicAdd(&cur[d>>6], 1);
    epk[pos] = (src[e]<<6) | (d&63);
  }
}
// in-bucket counting sort -> exact node-grouped CSR (rowptr, srcS) + dinv.
__global__ void k_bsort(const int* __restrict__ bucketStart, const int* __restrict__ epk,
                        int* __restrict__ srcS, int* __restrict__ rowptr,
                        float* __restrict__ dinv){
  __shared__ int hist[64], excl[64], cur[64];
  int tid = threadIdx.x;
  if(tid < 64) hist[tid] = 0;
  __syncthreads();
  int b = blockIdx.x, beg = bucketStart[b], end = bucketStart[b+1];
  for(int p=beg+tid; p<end; p+=256) atomicAdd(&hist[epk[p]&63], 1);
  __syncthreads();
  if(tid == 0){
    int run = 0;
    for(int j=0;j<64;j++){ excl[j] = run; run += hist[j]; }
  }
  __syncthreads();
  if(tid < 64){
    int g = b*64 + tid;
    if(g < NN){
      rowptr[g] = beg + excl[tid];
      dinv[g]   = rsqrtf((float)(hist[tid] + 1));   // +1 self-loop
    }
    cur[tid] = excl[tid];
  }
  if(b == 0 && tid == 0) rowptr[NN] = NE;
  __syncthreads();
  for(int p=beg+tid; p<end; p+=256){
    int pk = epk[p];
    int pos = atomicAdd(&cur[pk&63], 1);
    srcS[beg+pos] = pk>>6;
  }
}

// ---------------- layer 1 (propagate-then-transform; X has 2 channels) ----------------
__global__ void k_xd(const void* __restrict__ xv, const int* __restrict__ flag,
                     const float* __restrict__ dinv, float2* __restrict__ xd){
  int i = blockIdx.x*256 + threadIdx.x;
  if(i >= NN) return;
  float x0, x1;
  if(*flag){ float2 p = ((const float2*)xv)[i]; x0=p.x; x1=p.y; }
  else     { const bf16* xp=(const bf16*)xv; x0=b2f(xp[2*i]); x1=b2f(xp[2*i+1]); }
  float d = dinv[i];
  xd[i] = make_float2(x0*d, x1*d);
}
__global__ void k_prop_x(const int* __restrict__ rowptr, const int* __restrict__ srcS,
                         const float2* __restrict__ xd, float2* __restrict__ y){
  int i = blockIdx.x*256 + threadIdx.x;
  if(i >= NN) return;
  int beg = rowptr[i], end = rowptr[i+1];
  float2 self = xd[i];
  float ax0 = self.x, ay0 = self.y;
  float ax1=0,ay1=0, ax2=0,ay2=0, ax3=0,ay3=0;
  int p = beg;
  for(; p+4 <= end; p += 4){
    int s0=srcS[p], s1=srcS[p+1], s2=srcS[p+2], s3=srcS[p+3];
    float2 v0=xd[s0], v1=xd[s1], v2=xd[s2], v3=xd[s3];
    ax0+=v0.x; ay0+=v0.y; ax1+=v1.x; ay1+=v1.y;
    ax2+=v2.x; ay2+=v2.y; ax3+=v3.x; ay3+=v3.y;
  }
  for(; p<end; p++){ float2 v=xd[srcS[p]]; ax0+=v.x; ay0+=v.y; }
  y[i] = make_float2((ax0+ax1)+(ax2+ax3), (ay0+ay1)+(ay2+ay3));
}
__global__ void k_transform1b(const float2* __restrict__ y, const float* __restrict__ Wc,
                              const float* __restrict__ dinv, bf16* __restrict__ h){
  __shared__ float W1s[128];
  __shared__ float bs[64];
  if(threadIdx.x < 128) W1s[threadIdx.x] = Wc[W1F + threadIdx.x];
  if(threadIdx.x < 64)  bs[threadIdx.x]  = Wc[B1F + threadIdx.x];
  __syncthreads();
  int t = blockIdx.x*256 + threadIdx.x;   // grid NN*8 threads
  int i = t>>3, g = t&7;
  float2 yv = y[i];
  float d = dinv[i];
  us8_t o;
  #pragma unroll
  for(int j=0;j<8;j++){
    int c = g*8+j;
    o[j] = f2us(fmaxf(d*(yv.x*W1s[c] + yv.y*W1s[64+c]) + bs[c], 0.0f));
  }
  *(us8_t*)((unsigned short*)h + (size_t)i*64 + g*8) = o;
}

// ---------------- 64->64 transform (LDS-tiled GEMM, 4x4 tile/thread) ----------------
__global__ void __launch_bounds__(256) k_transform64(
    const bf16* __restrict__ h, const float* __restrict__ W,
    const float* __restrict__ dinv, bf16* __restrict__ s){
  __shared__ float Ws[64*64];
  __shared__ float hs[64][68];
  __shared__ float dl[64];
  int tid = threadIdx.x;
  for(int j=tid; j<4096; j+=256) Ws[j] = W[j];
  int row0 = blockIdx.x*64;
  if(tid < 64){ int r = row0+tid; dl[tid] = (r<NN)? dinv[r] : 0.0f; }
  for(int ch = tid; ch < 512; ch += 256){
    int r = ch>>3, c8 = (ch&7)*8;
    int gr = row0 + r;
    float f[8];
    if(gr < NN){
      us8_t v = *(const us8_t*)((const unsigned short*)h + (size_t)gr*64 + c8);
      #pragma unroll
      for(int j=0;j<8;j++) f[j] = us2f(v[j]);
    } else {
      #pragma unroll
      for(int j=0;j<8;j++) f[j] = 0.0f;
    }
    *(float4*)&hs[r][c8]   = make_float4(f[0],f[1],f[2],f[3]);
    *(float4*)&hs[r][c8+4] = make_float4(f[4],f[5],f[6],f[7]);
  }
  __syncthreads();
  int ty = tid>>4, tx = tid&15;
  float acc[4][4] = {{0}};
  #pragma unroll 8
  for(int k=0;k<64;k++){
    float4 b4 = *(const float4*)&Ws[k*64 + tx*4];
    float a0 = hs[ty*4+0][k];
    float a1 = hs[ty*4+1][k];
    float a2 = hs[ty*4+2][k];
    float a3 = hs[ty*4+3][k];
    acc[0][0] = fmaf(a0,b4.x,acc[0][0]); acc[0][1] = fmaf(a0,b4.y,acc[0][1]);
    acc[0][2] = fmaf(a0,b4.z,acc[0][2]); acc[0][3] = fmaf(a0,b4.w,acc[0][3]);
    acc[1][0] = fmaf(a1,b4.x,acc[1][0]); acc[1][1] = fmaf(a1,b4.y,acc[1][1]);
    acc[1][2] = fmaf(a1,b4.z,acc[1][2]); acc[1][3] = fmaf(a1,b4.w,acc[1][3]);
    acc[2][0] = fmaf(a2,b4.x,acc[2][0]); acc[2][1] = fmaf(a2,b4.y,acc[2][1]);
    acc[2][2] = fmaf(a2,b4.z,acc[2][2]); acc[2][3] = fmaf(a2,b4.w,acc[2][3]);
    acc[3][0] = fmaf(a3,b4.x,acc[3][0]); acc[3][1] = fmaf(a3,b4.y,acc[3][1]);
    acc[3][2] = fmaf(a3,b4.z,acc[3][2]); acc[3][3] = fmaf(a3,b4.w,acc[3][3]);
  }
  #pragma unroll
  for(int rr=0; rr<4; rr++){
    int r = row0 + ty*4 + rr;
    if(r < NN){
      float dv = dl[ty*4+rr];
      unsigned lo = f2us(acc[rr][0]*dv) | ((unsigned)f2us(acc[rr][1]*dv) << 16);
      unsigned hi = f2us(acc[rr][2]*dv) | ((unsigned)f2us(acc[rr][3]*dv) << 16);
      uint2 o; o.x = lo; o.y = hi;
      *(uint2*)((unsigned short*)s + (size_t)r*64 + tx*4) = o;
    }
  }
}

// ---------------- CSR aggregate + finalize: wave per node, 8 edges per wave-load ----------------
__global__ void __launch_bounds__(256) k_aggregate(
    const int* __restrict__ rowptr, const int* __restrict__ srcS,
    const bf16* __restrict__ s, const float* __restrict__ dinv,
    const float* __restrict__ bias, bf16* __restrict__ h){
  int wave = threadIdx.x>>6, lane = threadIdx.x&63;
  int i = blockIdx.x*4 + wave;            // grid = NN/4 = 25000 blocks
  if(i >= NN) return;
  int beg = rowptr[i], end = rowptr[i+1];
  int slot = lane>>3, oct = lane&7;
  const unsigned short* sp = (const unsigned short*)s;
  float a0[8] = {0,0,0,0,0,0,0,0};
  float a1[8] = {0,0,0,0,0,0,0,0};
  int p = beg;
  for(; p+16 <= end; p += 16){            // 16 edges in flight (2 per lane)
    int e0 = srcS[p + slot];
    int e1 = srcS[p + 8 + slot];
    us8_t v0 = *(const us8_t*)(sp + (size_t)e0*64 + oct*8);
    us8_t v1 = *(const us8_t*)(sp + (size_t)e1*64 + oct*8);
    #pragma unroll
    for(int j=0;j<8;j++){ a0[j] += us2f(v0[j]); a1[j] += us2f(v1[j]); }
  }
  for(; p+8 <= end; p += 8){
    int e0 = srcS[p + slot];
    us8_t v0 = *(const us8_t*)(sp + (size_t)e0*64 + oct*8);
    #pragma unroll
    for(int j=0;j<8;j++) a0[j] += us2f(v0[j]);
  }
  int rem = end - p;                      // 0..7 tail, one edge per low slot
  if(slot < rem){
    int e0 = srcS[p + slot];
    us8_t v0 = *(const us8_t*)(sp + (size_t)e0*64 + oct*8);
    #pragma unroll
    for(int j=0;j<8;j++) a1[j] += us2f(v0[j]);
  }
  // reduce across the 8 edge slots (lane bits 3,4,5)
  float c[8];
  #pragma unroll
  for(int j=0;j<8;j++){
    float v = a0[j] + a1[j];
    v += __shfl_xor(v, 8, 64);
    v += __shfl_xor(v, 16, 64);
    v += __shfl_xor(v, 32, 64);
    c[j] = v;
  }
  // self-loop + finalize
  us8_t sv = *(const us8_t*)(sp + (size_t)i*64 + oct*8);
  float dv = dinv[i];
  us8_t o;
  #pragma unroll
  for(int j=0;j<8;j++){
    float v = c[j] + us2f(sv[j]);
    o[j] = f2us(fmaxf(fmaf(dv, v, bias[oct*8+j]), 0.0f));
  }
  if(slot == 0)                           // lanes 0..7 store 128B contiguous
    *(us8_t*)((unsigned short*)h + (size_t)i*64 + oct*8) = o;
}

// ---------------- fc1: [NN x 64] @ [64 x 128] + b, relu -> f (bf16) ----------------
__global__ void __launch_bounds__(256) k_fc1(const bf16* __restrict__ h,
                                             const float* __restrict__ Wc,
                                             bf16* __restrict__ f){
  __shared__ float W1s[64*128];
  __shared__ float hs[64][68];
  __shared__ float bs[128];
  int tid = threadIdx.x;
  for(int j=tid; j<8192; j+=256) W1s[j] = Wc[FW1F+j];
  if(tid < 128) bs[tid] = Wc[FB1F+tid];
  int row0 = blockIdx.x*64;
  for(int ch = tid; ch < 512; ch += 256){
    int r = ch>>3, c8 = (ch&7)*8, gr = row0 + r;
    float fv[8];
    if(gr < NN){
      us8_t v = *(const us8_t*)((const unsigned short*)h + (size_t)gr*64 + c8);
      #pragma unroll
      for(int j=0;j<8;j++) fv[j] = us2f(v[j]);
    } else {
      #pragma unroll
      for(int j=0;j<8;j++) fv[j] = 0.0f;
    }
    *(float4*)&hs[r][c8]   = make_float4(fv[0],fv[1],fv[2],fv[3]);
    *(float4*)&hs[r][c8+4] = make_float4(fv[4],fv[5],fv[6],fv[7]);
  }
  __syncthreads();
  int ty = tid>>4, tx = tid&15;
  float acc[4][8] = {{0}};
  #pragma unroll 4
  for(int k=0;k<64;k++){
    float4 b0 = *(const float4*)&W1s[k*128 + tx*8];
    float4 b1 = *(const float4*)&W1s[k*128 + tx*8 + 4];
    float a0 = hs[ty*4+0][k], a1 = hs[ty*4+1][k];
    float a2 = hs[ty*4+2][k], a3 = hs[ty*4+3][k];
    acc[0][0]=fmaf(a0,b0.x,acc[0][0]); acc[0][1]=fmaf(a0,b0.y,acc[0][1]);
    acc[0][2]=fmaf(a0,b0.z,acc[0][2]); acc[0][3]=fmaf(a0,b0.w,acc[0][3]);
    acc[0][4]=fmaf(a0,b1.x,acc[0][4]); acc[0][5]=fmaf(a0,b1.y,acc[0][5]);
    acc[0][6]=fmaf(a0,b1.z,acc[0][6]); acc[0][7]=fmaf(a0,b1.w,acc[0][7]);
    acc[1][0]=fmaf(a1,b0.x,acc[1][0]); acc[1][1]=fmaf(a1,b0.y,acc[1][1]);
    acc[1][2]=fmaf(a1,b0.z,acc[1][2]); acc[1][3]=fmaf(a1,b0.w,acc[1][3]);
    acc[1][4]=fmaf(a1,b1.x,acc[1][4]); acc[1][5]=fmaf(a1,b1.y,acc[1][5]);
    acc[1][6]=fmaf(a1,b1.z,acc[1][6]); acc[1][7]=fmaf(a1,b1.w,acc[1][7]);
    acc[2][0]=fmaf(a2,b0.x,acc[2][0]); acc[2][1]=fmaf(a2,b0.y,acc[2][1]);
    acc[2][2]=fmaf(a2,b0.z,acc[2][2]); acc[2][3]=fmaf(a2,b0.w,acc[2][3]);
    acc[2][4]=fmaf(a2,b1.x,acc[2][4]); acc[2][5]=fmaf(a2,b1.y,acc[2][5]);
    acc[2][6]=fmaf(a2,b1.z,acc[2][6]); acc[2][7]=fmaf(a2,b1.w,acc[2][7]);
    acc[3][0]=fmaf(a3,b0.x,acc[3][0]); acc[3][1]=fmaf(a3,b0.y,acc[3][1]);
    acc[3][2]=fmaf(a3,b0.z,acc[3][2]); acc[3][3]=fmaf(a3,b0.w,acc[3][3]);
    acc[3][4]=fmaf(a3,b1.x,acc[3][4]); acc[3][5]=fmaf(a3,b1.y,acc[3][5]);
    acc[3][6]=fmaf(a3,b1.z,acc[3][6]); acc[3][7]=fmaf(a3,b1.w,acc[3][7]);
  }
  #pragma unroll
  for(int r=0;r<4;r++){
    int gr = row0 + ty*4 + r;
    if(gr < NN){
      us8_t o;
      #pragma unroll
      for(int j=0;j<8;j++) o[j] = f2us(fmaxf(acc[r][j] + bs[tx*8+j], 0.0f));
      *(us8_t*)((unsigned short*)f + (size_t)gr*128 + tx*8) = o;
    }
  }
}

// ---------------- fc2: [NN x 128] @ [128 x 32] + b -> out ----------------
__global__ void __launch_bounds__(256) k_fc2(const bf16* __restrict__ f,
                                             const float* __restrict__ Wc,
                                             const int* __restrict__ flag,
                                             void* __restrict__ outv){
  __shared__ float W2s[128*32];
  __shared__ float fs[64][132];
  __shared__ float bs[32];
  int tid = threadIdx.x;
  for(int j=tid; j<4096; j+=256) W2s[j] = Wc[FW2F+j];
  if(tid < 32) bs[tid] = Wc[FB2F+tid];
  int row0 = blockIdx.x*64;
  for(int ch = tid; ch < 1024; ch += 256){
    int r = ch>>4, c8 = (ch&15)*8, gr = row0 + r;
    float fv[8];
    if(gr < NN){
      us8_t v = *(const us8_t*)((const unsigned short*)f + (size_t)gr*128 + c8);
      #pragma unroll
      for(int j=0;j<8;j++) fv[j] = us2f(v[j]);
    } else {
      #pragma unroll
      for(int j=0;j<8;j++) fv[j] = 0.0f;
    }
    *(float4*)&fs[r][c8]   = make_float4(fv[0],fv[1],fv[2],fv[3]);
    *(float4*)&fs[r][c8+4] = make_float4(fv[4],fv[5],fv[6],fv[7]);
  }
  __syncthreads();
  int ty = tid>>3, tx = tid&7;
  float acc[2][4] = {{0}};
  #pragma unroll 8
  for(int k=0;k<128;k++){
    float4 b4 = *(const float4*)&W2s[k*32 + tx*4];
    float a0 = fs[ty*2+0][k], a1 = fs[ty*2+1][k];
    acc[0][0]=fmaf(a0,b4.x,acc[0][0]); acc[0][1]=fmaf(a0,b4.y,acc[0][1]);
    acc[0][2]=fmaf(a0,b4.z,acc[0][2]); acc[0][3]=fmaf(a0,b4.w,acc[0][3]);
    acc[1][0]=fmaf(a1,b4.x,acc[1][0]); acc[1][1]=fmaf(a1,b4.y,acc[1][1]);
    acc[1][2]=fmaf(a1,b4.z,acc[1][2]); acc[1][3]=fmaf(a1,b4.w,acc[1][3]);
  }
  int fl = *flag;
  #pragma unroll
  for(int r=0;r<2;r++){
    int gr = row0 + ty*2 + r;
    if(gr < NN){
      float o0 = acc[r][0]+bs[tx*4+0], o1 = acc[r][1]+bs[tx*4+1];
      float o2 = acc[r][2]+bs[tx*4+2], o3 = acc[r][3]+bs[tx*4+3];
      if(fl){
        *(float4*)((float*)outv + (size_t)gr*32 + tx*4) = make_float4(o0,o1,o2,o3);
      } else {
        unsigned lo = f2us(o0) | ((unsigned)f2us(o1)<<16);
        unsigned hi = f2us(o2) | ((unsigned)f2us(o3)<<16);
        uint2 o; o.x = lo; o.y = hi;
        *(uint2*)((unsigned short*)outv + (size_t)gr*32 + tx*4) = o;
      }
    }
  }
}

extern "C" void kernel_launch(void* const* d_in, const int* in_sizes, int n_in,
                              void* d_out, int out_size, void* d_ws, size_t ws_size,
                              hipStream_t stream){
  const void* x   = d_in[0];
  const int*  ei  = (const int*)d_in[1];
  const int* srcI = ei;        // edge_index[0]
  const int* dstI = ei + NE;   // edge_index[1]

  // workspace layout (bytes); total ~69 MB
  char*   base   = (char*)d_ws;
  int*    flag   = (int*)   (base + 0);          // 256
  float*  Wc     = (float*) (base + 256);        // 83840 -> 84096
  int*    bstart = (int*)   (base + 84224);      // 6256
  int*    cnt    = (int*)   (base + 90624);      // 1225392
  int*    tmpS   = (int*)   (base + 1316096);    // 1225392
  int*    bsum   = (int*)   (base + 2541568);    // 2048
  int*    boff   = (int*)   (base + 2543616);    // 2048
  float*  dinv   = (float*) (base + 2545664);    // 400000
  int*    rowptr = (int*)   (base + 2945664);    // 400004
  int*    epk    = (int*)   (base + 3345792);    // 6400000
  int*    srcS   = (int*)   (base + 9745792);    // 6400000
  float2* xd     = (float2*)(base + 16145792);   // 800000
  float2* y      = (float2*)(base + 16945792);   // 800000
  bf16*   s      = (bf16*)  (base + 17745792);   // 12800000
  bf16*   h      = (bf16*)  (base + 30545792);   // 12800000
  bf16*   f      = (bf16*)  (base + 43345792);   // 25600000 -> ends 68945792

  // dtype sniff + weight conversion (multi-block — round-10 fix: these were
  // single-block latency sinks at 70 µs each)
  k_flag0    <<<1, 64, 0, stream>>>(flag);
  k_sniffB   <<<98, 256, 0, stream>>>((const unsigned short*)x, flag);
  k_convert_w<<<(WTOT+255)/256, 256, 0, stream>>>(
      d_in[2], d_in[3], d_in[4], d_in[5], d_in[6],
      d_in[7], d_in[8], d_in[9], d_in[10], d_in[11], flag, Wc);

  // bucket-grouped build: hist -> parallel scan -> place -> in-bucket sort
  k_bhist <<<NBB, 512, 0, stream>>>(dstI, cnt);
  k_scanA <<<SCANB, 1024, 0, stream>>>(cnt, tmpS, bsum);
  k_scanB <<<1, 512, 0, stream>>>(bsum, boff);
  k_scanC <<<SCANB, 1024, 0, stream>>>(cnt, tmpS, boff, bstart);
  k_bplace<<<NBB, 512, 0, stream>>>(srcI, dstI, cnt, epk);
  k_bsort <<<NBUK, 256, 0, stream>>>(bstart, epk, srcS, rowptr, dinv);

  // layer 1 (2 -> 64): propagate x first (8B gathers), then transform
  k_xd         <<<(NN+255)/256, 256, 0, stream>>>(x, flag, dinv, xd);
  k_prop_x     <<<(NN+255)/256, 256, 0, stream>>>(rowptr, srcS, xd, y);
  k_transform1b<<<NN*8/256, 256, 0, stream>>>(y, Wc, dinv, h);

  // layer 2 (64 -> 64)
  k_transform64<<<(NN+63)/64, 256, 0, stream>>>(h, Wc+W2F, dinv, s);
  k_aggregate  <<<NN/4, 256, 0, stream>>>(rowptr, srcS, s, dinv, Wc+B2F, h);

  // layer 3 (64 -> 64)
  k_transform64<<<(NN+63)/64, 256, 0, stream>>>(h, Wc+W3F, dinv, s);
  k_aggregate  <<<NN/4, 256, 0, stream>>>(rowptr, srcS, s, dinv, Wc+B3F, h);

  // fc1 + fc2 (register-tiled GEMMs)
  k_fc1<<<(NN+63)/64, 256, 0, stream>>>(h, Wc, f);
  k_fc2<<<(NN+63)/64, 256, 0, stream>>>(f, Wc, flag, d_out);
}